// Round 20
// baseline (115.916 us; speedup 1.0000x reference)
//
#include <hip/hip_runtime.h>
#include <hip/hip_bf16.h>

// MHA forward: B=4, S=1024, D=1024, H=16, DK=64.
// v20: best-of-each composition — attn_v7 (R12, 4 WG/CU), gemm_proj v18
// (conflict-free interleaved LDS, 512t), gemm_out 512t (R19), prep/maskcvt/
// cvt_w unchanged.

typedef __bf16 bf16x8 __attribute__((ext_vector_type(8)));
typedef float f32x4 __attribute__((ext_vector_type(4)));
typedef unsigned short us8 __attribute__((ext_vector_type(8)));
typedef unsigned short us4 __attribute__((ext_vector_type(4)));

#define MFMA(a, b, c) __builtin_amdgcn_mfma_f32_16x16x32_bf16(a, b, c, 0, 0, 0)
#define EXP2(x) __builtin_amdgcn_exp2f(x)

__device__ __forceinline__ unsigned short f2b(float f) {
  return __builtin_bit_cast(unsigned short, __float2bfloat16(f));
}
__device__ __forceinline__ float b2f(unsigned short u) {
  return __builtin_bit_cast(float, (unsigned)u << 16);
}
__device__ __forceinline__ unsigned cvtpk(float lo, float hi) {
  unsigned r;
  asm("v_cvt_pk_bf16_f32 %0, %1, %2" : "=v"(r) : "v"(lo), "v"(hi));
  return r;
}
__device__ __forceinline__ bf16x8 ldbf8(const unsigned short* p) {
  return __builtin_bit_cast(bf16x8, *reinterpret_cast<const us8*>(p));
}
__device__ __forceinline__ us8 cvt8(float4 a, float4 b) {
  us8 o;
  o[0] = f2b(a.x); o[1] = f2b(a.y); o[2] = f2b(a.z); o[3] = f2b(a.w);
  o[4] = f2b(b.x); o[5] = f2b(b.y); o[6] = f2b(b.z); o[7] = f2b(b.w);
  return o;
}
__device__ __forceinline__ void glds16(const void* g, void* l) {
  __builtin_amdgcn_global_load_lds(
      (const __attribute__((address_space(1))) unsigned int*)g,
      (__attribute__((address_space(3))) unsigned int*)l, 16, 0, 0);
}

// prep: bid [0,1536): wq/wk/wv f32->bf16 -> Wb (3 x 1M elems, row-major).
//       bid [1536,3584): query -> Abfq; [3584,5632): key -> Abfk;
//       bid [5632,7680): value -> Abfv (launched only when ws is big enough).
__global__ __launch_bounds__(256)
void prep(const float* __restrict__ query, const float* __restrict__ key,
          const float* __restrict__ value, const float* __restrict__ wq,
          const float* __restrict__ wk, const float* __restrict__ wv,
          unsigned short* __restrict__ Abfq, unsigned short* __restrict__ Abfk,
          unsigned short* __restrict__ Abfv, unsigned short* __restrict__ Wb) {
  const int bid = blockIdx.x, tid = threadIdx.x;
  const float* src;
  unsigned short* dst;
  size_t off;
  if (bid < 1536) {
    const int widx = bid >> 9;
    src = (widx == 0) ? wq : (widx == 1) ? wk : wv;
    dst = Wb + (size_t)widx * 1048576;
    off = (size_t)(bid & 511) * 2048 + tid * 8;
  } else if (bid < 3584) {
    src = query; dst = Abfq; off = (size_t)(bid - 1536) * 2048 + tid * 8;
  } else if (bid < 5632) {
    src = key; dst = Abfk; off = (size_t)(bid - 3584) * 2048 + tid * 8;
  } else {
    src = value; dst = Abfv; off = (size_t)(bid - 5632) * 2048 + tid * 8;
  }
  const float4* p = reinterpret_cast<const float4*>(src + off);
  *reinterpret_cast<us8*>(dst + off) = cvt8(p[0], p[1]);
}

// mask[b][q][k] -> Mf in swapped QK^T C-frag order (C[k][q], q=lane&15).
// Fixed-offset softmax: unmasked = bf16(-24), masked = bf16(-1.44e9) = 0xCEAC.
__global__ __launch_bounds__(256)
void maskcvt(const int* __restrict__ mask, unsigned short* __restrict__ Mf) {
  const int idx = blockIdx.x * 256 + threadIdx.x;
  const int wl = idx & 63, tile = idx >> 6;
  const int kt = tile & 63, qt = (tile >> 6) & 63, b = tile >> 12;
  const int lr = wl & 15, lg = wl >> 4;
  const int4 mv = *reinterpret_cast<const int4*>(
      mask + (size_t)(b * 1024 + qt * 16 + lr) * 1024 + kt * 16 + lg * 4);
  us4 o;
  o[0] = mv.x ? 0xCEACu : 0xC1C0u;
  o[1] = mv.y ? 0xCEACu : 0xC1C0u;
  o[2] = mv.z ? 0xCEACu : 0xC1C0u;
  o[3] = mv.w ? 0xCEACu : 0xC1C0u;
  *reinterpret_cast<us4*>(Mf + (size_t)idx * 4) = o;
}

// single f32->bf16 1M convert (wo, after attn frees Vf slot)
__global__ __launch_bounds__(256)
void cvt_w(const float* __restrict__ src, unsigned short* __restrict__ dst) {
  const size_t off = (size_t)blockIdx.x * 2048 + threadIdx.x * 8;
  const float4* p = reinterpret_cast<const float4*>(src + off);
  *reinterpret_cast<us8*>(dst + off) = cvt8(p[0], p[1]);
}

// Projection GEMM v18 (unchanged): BM=128, BN=128, BK=32; 512 threads = 8
// waves (2x4); dbuf 32KB LDS; row-pair-interleaved conflict-free layout.
__global__ __launch_bounds__(512, 6)
void gemm_proj(const unsigned short* __restrict__ Aq,
               const unsigned short* __restrict__ Ak,
               const unsigned short* __restrict__ Av_bf,
               const float* __restrict__ Av_f32,
               const unsigned short* __restrict__ Wb,
               const float* __restrict__ bq, const float* __restrict__ bk,
               const float* __restrict__ bv, unsigned short* __restrict__ Qb,
               unsigned short* __restrict__ Kf, unsigned short* __restrict__ Vf,
               float qscale) {
  constexpr int K = 1024, N = 1024;
  __shared__ __align__(16) unsigned short As[2][128 * 32];
  __shared__ __align__(16) unsigned short Bs[2][128 * 32];
  const int lid = blockIdx.x + (blockIdx.y << 5) + (blockIdx.z << 8);
  const int xcd = lid & 7, slot = lid >> 3;
  const int chunk = ((slot >> 3) << 3) + xcd;
  const int z = chunk >> 5;
  const int bm = (chunk & 31) * 128;
  const int bn = (slot & 7) * 128;

  const unsigned short* Abf = (z == 0) ? Aq : (z == 1) ? Ak : Av_bf;
  const bool f32path = (z == 2) && (Av_bf == nullptr);
  const unsigned short* Bw = Wb + (size_t)z * 1048576;
  const float* bias = (z == 0) ? bq : (z == 1) ? bk : bv;
  const int t = threadIdx.x;
  const int w = t >> 6, lane = t & 63, lr = lane & 15, lg = lane >> 4;
  const int wr = w >> 2, wc = w & 3;

  const int sline = t >> 3;
  const int su = (t & 7) ^ (sline & 7);
  const int srow = sline * 2 + (su >> 2);
  const int scol = (su & 3) * 8;

  f32x4 acc[4][2];
#pragma unroll
  for (int m = 0; m < 4; ++m)
#pragma unroll
    for (int n = 0; n < 2; ++n) acc[m][n] = f32x4{0.f, 0.f, 0.f, 0.f};

  auto stageA = [&](int k0, int buf) {
    const char* g = (const char*)(Abf + (size_t)(bm + srow) * 1024 + k0 + scol);
    char* l = (char*)&As[buf][0] + (w * 64) * 16;
    glds16(g, l);
  };
  auto stageB = [&](int k0, int buf) {
    const char* g = (const char*)(Bw + (size_t)(bn + srow) * 1024 + k0 + scol);
    char* l = (char*)&Bs[buf][0] + (w * 64) * 16;
    glds16(g, l);
  };
#define STA8(buf, v)                                                           \
  { *reinterpret_cast<us8*>((char*)&As[buf][0] + t * 16) = (v); }
#define RDOFF(row) (((row) >> 1) * 128 +                                       \
                    (((lg | (((row) & 1) << 2)) ^ (((row) >> 1) & 7)) * 16))

  if (f32path) {
    const float4* p =
        reinterpret_cast<const float4*>(Av_f32 + (size_t)(bm + srow) * K + scol);
    STA8(0, cvt8(p[0], p[1]));
  } else {
    stageA(0, 0);
  }
  stageB(0, 0);
  __syncthreads();

  for (int c = 0; c < 32; ++c) {
    const int buf = c & 1;
    float4 fa[2];
    if (c < 31) {
      const int k1 = (c + 1) * 32;
      if (f32path) {
        const float4* p = reinterpret_cast<const float4*>(
            Av_f32 + (size_t)(bm + srow) * K + k1 + scol);
        fa[0] = p[0];
        fa[1] = p[1];
      } else {
        stageA(k1, buf ^ 1);
      }
      stageB(k1, buf ^ 1);
    }
    {
      bf16x8 af[4], bfr[2];
#pragma unroll
      for (int m = 0; m < 4; ++m) {
        const int row = wr * 64 + m * 16 + lr;
        af[m] = ldbf8((const unsigned short*)((char*)&As[buf][0] + RDOFF(row)));
      }
#pragma unroll
      for (int n = 0; n < 2; ++n) {
        const int row = wc * 32 + n * 16 + lr;
        bfr[n] = ldbf8((const unsigned short*)((char*)&Bs[buf][0] + RDOFF(row)));
      }
#pragma unroll
      for (int m = 0; m < 4; ++m)
#pragma unroll
        for (int n = 0; n < 2; ++n) acc[m][n] = MFMA(af[m], bfr[n], acc[m][n]);
    }
    if (c < 31 && f32path) {
      STA8(buf ^ 1, cvt8(fa[0], fa[1]));
    }
    __syncthreads();
  }
#undef STA8
#undef RDOFF

#pragma unroll
  for (int m = 0; m < 4; ++m) {
    const int mr = bm + wr * 64 + m * 16 + lg * 4;
#pragma unroll
    for (int nt = 0; nt < 2; ++nt) {
      const int n = bn + wc * 32 + nt * 16 + lr;
      const float bb = bias[n];
      if (z == 0) {
#pragma unroll
        for (int r = 0; r < 4; ++r)
          Qb[(size_t)(mr + r) * N + n] = f2b((acc[m][nt][r] + bb) * qscale);
      } else if (z == 1) {
        // Kf: K[bh][s][d] -> bh*65536 + (d>>5)*32768 + (s>>4)*512
        //     + ((s&15)|(((d>>3)&3)<<4))*8 + (d&7)
        const int b2 = mr >> 10, s0 = mr & 1023, hh = n >> 6, dd = n & 63;
        const size_t base = (size_t)(b2 * 16 + hh) * 65536 + (size_t)(dd >> 5) * 32768 +
                            (size_t)(s0 >> 4) * 512 +
                            (size_t)((s0 & 15) | (((dd >> 3) & 3) << 4)) * 8 + (dd & 7);
#pragma unroll
        for (int r = 0; r < 4; ++r) Kf[base + r * 8] = f2b(acc[m][nt][r] + bb);
      } else {
        // Vf: V[bh][s][d] -> bh*65536 + (s>>5)*2048 + (d>>4)*512
        //     + ((d&15)|(((s>>3)&3)<<4))*8 + (s&7)
        const int b2 = mr >> 10, s0 = mr & 1023, hh = n >> 6, dd = n & 63;
        const size_t base = (size_t)(b2 * 16 + hh) * 65536 + (size_t)(s0 >> 5) * 2048 +
                            (size_t)(dd >> 4) * 512 +
                            (size_t)((dd & 15) | (((s0 >> 3) & 3) << 4)) * 8 + (s0 & 7);
        us4 pk;
#pragma unroll
        for (int r = 0; r < 4; ++r) pk[r] = f2b(acc[m][nt][r] + bb);
        *reinterpret_cast<us4*>(&Vf[base]) = pk;
      }
    }
  }
}

// Output projection v19 (kept): BM=128, BN=64, BK=64; 512 threads = 8 waves
// (4x2), wave tile 32x32 -> 16 waves/CU. dbuf glds staging + 3-bit swizzle.
__global__ __launch_bounds__(512, 4)
void gemm_out(const unsigned short* __restrict__ A, const unsigned short* __restrict__ Bw,
              const float* __restrict__ bias, float* __restrict__ Out) {
  constexpr int K = 1024, N = 1024;
  __shared__ __align__(16) unsigned short As[2][128 * 64];
  __shared__ __align__(16) unsigned short Bs[2][64 * 64];
  const int lid = blockIdx.x + (blockIdx.y << 5);
  const int xcd = lid & 7, slot = lid >> 3;
  const int chunk = ((slot >> 5) << 3) + xcd;
  const int pos = slot & 31;
  const int bm = ((chunk << 1) + (pos >> 4)) * 128;
  const int bn = (pos & 15) * 64;
  const int t = threadIdx.x;
  const int w = t >> 6, lane = t & 63, lr = lane & 15, lg = lane >> 4;
  const int wr = w >> 1, wc = w & 1;  // 4x2 wave grid
  const int swzc = (lr & 7) << 4;

  f32x4 acc[2][2];
#pragma unroll
  for (int m = 0; m < 2; ++m)
#pragma unroll
    for (int n = 0; n < 2; ++n) acc[m][n] = f32x4{0.f, 0.f, 0.f, 0.f};

  auto stageA = [&](int k0, int buf) {
#pragma unroll
    for (int it = 0; it < 2; ++it) {
      const int s = it * 512 + t, row = s >> 3, cb = (s & 7) * 16;
      const char* g = (const char*)A + ((size_t)(bm + row) * 1024 + k0) * 2 +
                      (cb ^ ((row & 7) << 4));
      char* l = (char*)&As[buf][0] + (it * 512 + w * 64) * 16;
      glds16(g, l);
    }
  };
  auto stageB = [&](int k0, int buf) {
    const int s = t, row = s >> 3, cb = (s & 7) * 16;
    const char* g = (const char*)Bw + ((size_t)(bn + row) * 1024 + k0) * 2 +
                    (cb ^ ((row & 7) << 4));
    char* l = (char*)&Bs[buf][0] + (w * 64) * 16;
    glds16(g, l);
  };

  stageA(0, 0);
  stageB(0, 0);
  __syncthreads();

  for (int c = 0; c < 16; ++c) {
    const int buf = c & 1;
    if (c < 15) {
      const int k1 = (c + 1) * 64;
      stageA(k1, buf ^ 1);
      stageB(k1, buf ^ 1);
    }
#pragma unroll
    for (int h2 = 0; h2 < 2; ++h2) {
      bf16x8 af[2], bfr[2];
#pragma unroll
      for (int m = 0; m < 2; ++m) {
        const int row = wr * 32 + m * 16 + lr;
        af[m] = ldbf8((const unsigned short*)((char*)&As[buf][0] + row * 128 +
                                              ((h2 * 64 + lg * 16) ^ swzc)));
      }
#pragma unroll
      for (int n = 0; n < 2; ++n) {
        const int row = wc * 32 + n * 16 + lr;
        bfr[n] = ldbf8((const unsigned short*)((char*)&Bs[buf][0] + row * 128 +
                                               ((h2 * 64 + lg * 16) ^ swzc)));
      }
#pragma unroll
      for (int m = 0; m < 2; ++m)
#pragma unroll
        for (int n = 0; n < 2; ++n) acc[m][n] = MFMA(af[m], bfr[n], acc[m][n]);
    }
    __syncthreads();
  }

#pragma unroll
  for (int m = 0; m < 2; ++m) {
    const int mr = bm + wr * 32 + m * 16 + lg * 4;
#pragma unroll
    for (int nt = 0; nt < 2; ++nt) {
      const int n = bn + wc * 32 + nt * 16 + lr;
      const float bb = bias[n];
#pragma unroll
      for (int r = 0; r < 4; ++r) Out[(size_t)(mr + r) * N + n] = acc[m][nt][r] + bb;
    }
  }
}

// Flash attention v7 (R12, the measured best): WG-shared K/V LDS staging
// (glds dbuf), fixed-offset softmax via Mf, cvt_pk P-pack, setprio. 16 q/wave.
__global__ __launch_bounds__(256)
void attn_v7(const unsigned short* __restrict__ Qb,
             const unsigned short* __restrict__ Kf,
             const unsigned short* __restrict__ Vf,
             const unsigned short* __restrict__ Mf,
             unsigned short* __restrict__ ctx) {
  __shared__ __align__(16) unsigned short S[2][8192];
  __shared__ __align__(16) unsigned short sP[4][16 * 64];
  const int lid = blockIdx.x + (blockIdx.y << 6);
  const int xcd = lid & 7, slot = lid >> 3;
  const int bh = ((slot >> 4) << 3) + xcd;
  const int qb = slot & 15;
  const int b = bh >> 4, h = bh & 15;
  const int t = threadIdx.x, w = t >> 6, wl = t & 63, lr = wl & 15, lg = wl >> 4;
  const int q0 = qb * 64 + w * 16;
  const int swz = (lr & 7) << 4;

  const unsigned short* qp = Qb + (size_t)(b * 1024 + q0 + lr) * 1024 + h * 64 + lg * 8;
  const bf16x8 bq0 = ldbf8(qp);
  const bf16x8 bq1 = ldbf8(qp + 32);

  const unsigned short* KfB = Kf + (size_t)bh * 65536;
  const unsigned short* VfB = Vf + (size_t)bh * 65536;
  const unsigned short* mfp = Mf + (size_t)((b * 64 + qb * 4 + w) * 64) * 256 + wl * 4;

  f32x4 O[4];
  float l_ = 0.f;
#pragma unroll
  for (int dt = 0; dt < 4; ++dt) O[dt] = f32x4{0.f, 0.f, 0.f, 0.f};
  unsigned short* sp = &sP[w][0];

  auto stage = [&](int kc, int buf) {
    const unsigned short* srcs[4] = {KfB + kc * 2048, KfB + 32768 + kc * 2048,
                                     VfB + kc * 4096, VfB + kc * 4096 + 2048};
#pragma unroll
    for (int r = 0; r < 4; ++r) {
      const char* g = (const char*)(srcs[r] + (size_t)t * 8);
      char* l = (char*)&S[buf][r * 2048 + w * 512];
      glds16(g, l);
    }
  };

  stage(0, 0);
  __syncthreads();

  for (int kc = 0; kc < 16; ++kc) {
    const int buf = kc & 1;
    if (kc < 15) stage(kc + 1, buf ^ 1);

    us4 mk[4];
#pragma unroll
    for (int t4 = 0; t4 < 4; ++t4)
      mk[t4] = *reinterpret_cast<const us4*>(mfp + (size_t)(kc * 4 + t4) * 256);

    bf16x8 ak[4][2];
#pragma unroll
    for (int t4 = 0; t4 < 4; ++t4) {
      ak[t4][0] = ldbf8(&S[buf][t4 * 512 + wl * 8]);
      ak[t4][1] = ldbf8(&S[buf][2048 + t4 * 512 + wl * 8]);
    }

    f32x4 sc[4];
    __builtin_amdgcn_s_setprio(1);
#pragma unroll
    for (int t4 = 0; t4 < 4; ++t4) {
      f32x4 a;
#pragma unroll
      for (int r = 0; r < 4; ++r) a[r] = b2f(mk[t4][r]);
      a = MFMA(ak[t4][0], bq0, a);
      a = MFMA(ak[t4][1], bq1, a);
      sc[t4] = a;
    }
    __builtin_amdgcn_s_setprio(0);

    float ps = 0.f;
#pragma unroll
    for (int t4 = 0; t4 < 4; ++t4) {
      const float e0 = EXP2(sc[t4][0]), e1 = EXP2(sc[t4][1]);
      const float e2 = EXP2(sc[t4][2]), e3 = EXP2(sc[t4][3]);
      ps += (e0 + e1) + (e2 + e3);
      uint2 pw;
      pw.x = cvtpk(e0, e1);
      pw.y = cvtpk(e2, e3);
      *reinterpret_cast<uint2*>((char*)sp + lr * 128 + ((t4 * 32 + lg * 8) ^ swz)) = pw;
    }
    ps += __shfl_xor(ps, 16);
    ps += __shfl_xor(ps, 32);
    l_ += ps;

    __builtin_amdgcn_s_setprio(1);
#pragma unroll
    for (int ks = 0; ks < 2; ++ks) {
      bf16x8 ap =
          ldbf8((const unsigned short*)((char*)sp + lr * 128 + ((ks * 64 + lg * 16) ^ swz)));
#pragma unroll
      for (int dt = 0; dt < 4; ++dt) {
        bf16x8 bv = ldbf8(&S[buf][4096 + ks * 2048 + dt * 512 + wl * 8]);
        O[dt] = MFMA(ap, bv, O[dt]);
      }
    }
    __builtin_amdgcn_s_setprio(0);

    __syncthreads();
  }

  float linv[4];
#pragma unroll
  for (int r = 0; r < 4; ++r) linv[r] = 1.0f / __shfl(l_, lg * 4 + r);
#pragma unroll
  for (int dt = 0; dt < 4; ++dt)
#pragma unroll
    for (int r = 0; r < 4; ++r)
      ctx[(size_t)(b * 1024 + q0 + lg * 4 + r) * 1024 + h * 64 + dt * 16 + lr] =
          f2b(O[dt][r] * linv[r]);
}

extern "C" void kernel_launch(void* const* d_in, const int* in_sizes, int n_in,
                              void* d_out, int out_size, void* d_ws, size_t ws_size,
                              hipStream_t stream) {
  const float* query = (const float*)d_in[0];
  const float* key   = (const float*)d_in[1];
  const float* value = (const float*)d_in[2];
  const int*   mask  = (const int*)d_in[3];
  const float* wq = (const float*)d_in[4];
  const float* bq = (const float*)d_in[5];
  const float* wk = (const float*)d_in[6];
  const float* bk = (const float*)d_in[7];
  const float* wv = (const float*)d_in[8];
  const float* bv = (const float*)d_in[9];
  const float* wo = (const float*)d_in[10];
  const float* bo = (const float*)d_in[11];
  float* out = (float*)d_out;

  // ws [0..32MB): Qb, Kf, Vf, ctx (bf16, 8MB each). ctx slot doubles as Abfk
  // during the projection. d_out: Abfq [0..8M) then Mf overlays it; Wb [8..14M).
  // Abfv at ws+32MB only if ws_size >= 40MB. wo(bf16) -> Vf slot after attn.
  const size_t SZ = (size_t)4096 * 1024;
  unsigned short* Qb   = (unsigned short*)d_ws;
  unsigned short* Kf   = Qb + SZ;
  unsigned short* Vf   = Kf + SZ;
  unsigned short* ctx  = Vf + SZ;
  unsigned short* Abfq = (unsigned short*)d_out;
  unsigned short* Wb   = Abfq + SZ;
  unsigned short* Mf   = (unsigned short*)d_out;  // after projection
  unsigned short* Abfk = ctx;                     // before attn
  const bool big = ws_size >= (size_t)40 * 1024 * 1024;
  unsigned short* Abfv = big ? (ctx + SZ) : nullptr;  // ws+32MB
  unsigned short* Wob  = Vf;                          // after attn

  const float qscale = 0.125f * 1.4426950408889634f;  // 1/sqrt(64) * log2(e)
  dim3 blk(256);
  prep<<<big ? 7680 : 5632, blk, 0, stream>>>(query, key, value, wq, wk, wv,
                                              Abfq, Abfk, Abfv, Wb);
  gemm_proj<<<dim3(32, 8, 3), dim3(512), 0, stream>>>(Abfq, Abfk, Abfv, value, Wb,
                                                      bq, bk, bv, Qb, Kf, Vf, qscale);
  maskcvt<<<4096, blk, 0, stream>>>(mask, Mf);
  attn_v7<<<dim3(64, 16), blk, 0, stream>>>(Qb, Kf, Vf, Mf, ctx);
  cvt_w<<<512, blk, 0, stream>>>(wo, Wob);
  gemm_out<<<dim3(32, 16), dim3(512), 0, stream>>>(ctx, Wob, bo, out);
}

// Round 21
// 114.534 us; speedup vs baseline: 1.0121x; 1.0121x over previous
//
#include <hip/hip_runtime.h>
#include <hip/hip_bf16.h>

// MHA forward: B=4, S=1024, D=1024, H=16, DK=64.
// v21: R20 base + (a) attn l-reduction hoisted out of chunk loop (per-lane
// accumulate, one 2-shfl reduce in epilogue); (b) cvt_w dispatch removed —
// gemm_out stages wo directly from f32 (reg-staged convert, T14 split).

typedef __bf16 bf16x8 __attribute__((ext_vector_type(8)));
typedef float f32x4 __attribute__((ext_vector_type(4)));
typedef unsigned short us8 __attribute__((ext_vector_type(8)));
typedef unsigned short us4 __attribute__((ext_vector_type(4)));

#define MFMA(a, b, c) __builtin_amdgcn_mfma_f32_16x16x32_bf16(a, b, c, 0, 0, 0)
#define EXP2(x) __builtin_amdgcn_exp2f(x)

__device__ __forceinline__ unsigned short f2b(float f) {
  return __builtin_bit_cast(unsigned short, __float2bfloat16(f));
}
__device__ __forceinline__ float b2f(unsigned short u) {
  return __builtin_bit_cast(float, (unsigned)u << 16);
}
__device__ __forceinline__ unsigned cvtpk(float lo, float hi) {
  unsigned r;
  asm("v_cvt_pk_bf16_f32 %0, %1, %2" : "=v"(r) : "v"(lo), "v"(hi));
  return r;
}
__device__ __forceinline__ bf16x8 ldbf8(const unsigned short* p) {
  return __builtin_bit_cast(bf16x8, *reinterpret_cast<const us8*>(p));
}
__device__ __forceinline__ us8 cvt8(float4 a, float4 b) {
  us8 o;
  o[0] = f2b(a.x); o[1] = f2b(a.y); o[2] = f2b(a.z); o[3] = f2b(a.w);
  o[4] = f2b(b.x); o[5] = f2b(b.y); o[6] = f2b(b.z); o[7] = f2b(b.w);
  return o;
}
__device__ __forceinline__ void glds16(const void* g, void* l) {
  __builtin_amdgcn_global_load_lds(
      (const __attribute__((address_space(1))) unsigned int*)g,
      (__attribute__((address_space(3))) unsigned int*)l, 16, 0, 0);
}

// prep: bid [0,1536): wq/wk/wv f32->bf16 -> Wb (3 x 1M elems, row-major).
//       bid [1536,3584): query -> Abfq; [3584,5632): key -> Abfk;
//       bid [5632,7680): value -> Abfv (launched only when ws is big enough).
__global__ __launch_bounds__(256)
void prep(const float* __restrict__ query, const float* __restrict__ key,
          const float* __restrict__ value, const float* __restrict__ wq,
          const float* __restrict__ wk, const float* __restrict__ wv,
          unsigned short* __restrict__ Abfq, unsigned short* __restrict__ Abfk,
          unsigned short* __restrict__ Abfv, unsigned short* __restrict__ Wb) {
  const int bid = blockIdx.x, tid = threadIdx.x;
  const float* src;
  unsigned short* dst;
  size_t off;
  if (bid < 1536) {
    const int widx = bid >> 9;
    src = (widx == 0) ? wq : (widx == 1) ? wk : wv;
    dst = Wb + (size_t)widx * 1048576;
    off = (size_t)(bid & 511) * 2048 + tid * 8;
  } else if (bid < 3584) {
    src = query; dst = Abfq; off = (size_t)(bid - 1536) * 2048 + tid * 8;
  } else if (bid < 5632) {
    src = key; dst = Abfk; off = (size_t)(bid - 3584) * 2048 + tid * 8;
  } else {
    src = value; dst = Abfv; off = (size_t)(bid - 5632) * 2048 + tid * 8;
  }
  const float4* p = reinterpret_cast<const float4*>(src + off);
  *reinterpret_cast<us8*>(dst + off) = cvt8(p[0], p[1]);
}

// mask[b][q][k] -> Mf in swapped QK^T C-frag order (C[k][q], q=lane&15).
// Fixed-offset softmax: unmasked = bf16(-24), masked = bf16(-1.44e9) = 0xCEAC.
__global__ __launch_bounds__(256)
void maskcvt(const int* __restrict__ mask, unsigned short* __restrict__ Mf) {
  const int idx = blockIdx.x * 256 + threadIdx.x;
  const int wl = idx & 63, tile = idx >> 6;
  const int kt = tile & 63, qt = (tile >> 6) & 63, b = tile >> 12;
  const int lr = wl & 15, lg = wl >> 4;
  const int4 mv = *reinterpret_cast<const int4*>(
      mask + (size_t)(b * 1024 + qt * 16 + lr) * 1024 + kt * 16 + lg * 4);
  us4 o;
  o[0] = mv.x ? 0xCEACu : 0xC1C0u;
  o[1] = mv.y ? 0xCEACu : 0xC1C0u;
  o[2] = mv.z ? 0xCEACu : 0xC1C0u;
  o[3] = mv.w ? 0xCEACu : 0xC1C0u;
  *reinterpret_cast<us4*>(Mf + (size_t)idx * 4) = o;
}

// Projection GEMM v18 (unchanged): BM=128, BN=128, BK=32; 512 threads = 8
// waves (2x4); dbuf 32KB LDS; row-pair-interleaved conflict-free layout.
__global__ __launch_bounds__(512, 6)
void gemm_proj(const unsigned short* __restrict__ Aq,
               const unsigned short* __restrict__ Ak,
               const unsigned short* __restrict__ Av_bf,
               const float* __restrict__ Av_f32,
               const unsigned short* __restrict__ Wb,
               const float* __restrict__ bq, const float* __restrict__ bk,
               const float* __restrict__ bv, unsigned short* __restrict__ Qb,
               unsigned short* __restrict__ Kf, unsigned short* __restrict__ Vf,
               float qscale) {
  constexpr int K = 1024, N = 1024;
  __shared__ __align__(16) unsigned short As[2][128 * 32];
  __shared__ __align__(16) unsigned short Bs[2][128 * 32];
  const int lid = blockIdx.x + (blockIdx.y << 5) + (blockIdx.z << 8);
  const int xcd = lid & 7, slot = lid >> 3;
  const int chunk = ((slot >> 3) << 3) + xcd;
  const int z = chunk >> 5;
  const int bm = (chunk & 31) * 128;
  const int bn = (slot & 7) * 128;

  const unsigned short* Abf = (z == 0) ? Aq : (z == 1) ? Ak : Av_bf;
  const bool f32path = (z == 2) && (Av_bf == nullptr);
  const unsigned short* Bw = Wb + (size_t)z * 1048576;
  const float* bias = (z == 0) ? bq : (z == 1) ? bk : bv;
  const int t = threadIdx.x;
  const int w = t >> 6, lane = t & 63, lr = lane & 15, lg = lane >> 4;
  const int wr = w >> 2, wc = w & 3;

  const int sline = t >> 3;
  const int su = (t & 7) ^ (sline & 7);
  const int srow = sline * 2 + (su >> 2);
  const int scol = (su & 3) * 8;

  f32x4 acc[4][2];
#pragma unroll
  for (int m = 0; m < 4; ++m)
#pragma unroll
    for (int n = 0; n < 2; ++n) acc[m][n] = f32x4{0.f, 0.f, 0.f, 0.f};

  auto stageA = [&](int k0, int buf) {
    const char* g = (const char*)(Abf + (size_t)(bm + srow) * 1024 + k0 + scol);
    char* l = (char*)&As[buf][0] + (w * 64) * 16;
    glds16(g, l);
  };
  auto stageB = [&](int k0, int buf) {
    const char* g = (const char*)(Bw + (size_t)(bn + srow) * 1024 + k0 + scol);
    char* l = (char*)&Bs[buf][0] + (w * 64) * 16;
    glds16(g, l);
  };
#define STA8(buf, v)                                                           \
  { *reinterpret_cast<us8*>((char*)&As[buf][0] + t * 16) = (v); }
#define RDOFF(row) (((row) >> 1) * 128 +                                       \
                    (((lg | (((row) & 1) << 2)) ^ (((row) >> 1) & 7)) * 16))

  if (f32path) {
    const float4* p =
        reinterpret_cast<const float4*>(Av_f32 + (size_t)(bm + srow) * K + scol);
    STA8(0, cvt8(p[0], p[1]));
  } else {
    stageA(0, 0);
  }
  stageB(0, 0);
  __syncthreads();

  for (int c = 0; c < 32; ++c) {
    const int buf = c & 1;
    float4 fa[2];
    if (c < 31) {
      const int k1 = (c + 1) * 32;
      if (f32path) {
        const float4* p = reinterpret_cast<const float4*>(
            Av_f32 + (size_t)(bm + srow) * K + k1 + scol);
        fa[0] = p[0];
        fa[1] = p[1];
      } else {
        stageA(k1, buf ^ 1);
      }
      stageB(k1, buf ^ 1);
    }
    {
      bf16x8 af[4], bfr[2];
#pragma unroll
      for (int m = 0; m < 4; ++m) {
        const int row = wr * 64 + m * 16 + lr;
        af[m] = ldbf8((const unsigned short*)((char*)&As[buf][0] + RDOFF(row)));
      }
#pragma unroll
      for (int n = 0; n < 2; ++n) {
        const int row = wc * 32 + n * 16 + lr;
        bfr[n] = ldbf8((const unsigned short*)((char*)&Bs[buf][0] + RDOFF(row)));
      }
#pragma unroll
      for (int m = 0; m < 4; ++m)
#pragma unroll
        for (int n = 0; n < 2; ++n) acc[m][n] = MFMA(af[m], bfr[n], acc[m][n]);
    }
    if (c < 31 && f32path) {
      STA8(buf ^ 1, cvt8(fa[0], fa[1]));
    }
    __syncthreads();
  }
#undef STA8
#undef RDOFF

#pragma unroll
  for (int m = 0; m < 4; ++m) {
    const int mr = bm + wr * 64 + m * 16 + lg * 4;
#pragma unroll
    for (int nt = 0; nt < 2; ++nt) {
      const int n = bn + wc * 32 + nt * 16 + lr;
      const float bb = bias[n];
      if (z == 0) {
#pragma unroll
        for (int r = 0; r < 4; ++r)
          Qb[(size_t)(mr + r) * N + n] = f2b((acc[m][nt][r] + bb) * qscale);
      } else if (z == 1) {
        // Kf: K[bh][s][d] -> bh*65536 + (d>>5)*32768 + (s>>4)*512
        //     + ((s&15)|(((d>>3)&3)<<4))*8 + (d&7)
        const int b2 = mr >> 10, s0 = mr & 1023, hh = n >> 6, dd = n & 63;
        const size_t base = (size_t)(b2 * 16 + hh) * 65536 + (size_t)(dd >> 5) * 32768 +
                            (size_t)(s0 >> 4) * 512 +
                            (size_t)((s0 & 15) | (((dd >> 3) & 3) << 4)) * 8 + (dd & 7);
#pragma unroll
        for (int r = 0; r < 4; ++r) Kf[base + r * 8] = f2b(acc[m][nt][r] + bb);
      } else {
        // Vf: V[bh][s][d] -> bh*65536 + (s>>5)*2048 + (d>>4)*512
        //     + ((d&15)|(((s>>3)&3)<<4))*8 + (s&7)
        const int b2 = mr >> 10, s0 = mr & 1023, hh = n >> 6, dd = n & 63;
        const size_t base = (size_t)(b2 * 16 + hh) * 65536 + (size_t)(s0 >> 5) * 2048 +
                            (size_t)(dd >> 4) * 512 +
                            (size_t)((dd & 15) | (((s0 >> 3) & 3) << 4)) * 8 + (s0 & 7);
        us4 pk;
#pragma unroll
        for (int r = 0; r < 4; ++r) pk[r] = f2b(acc[m][nt][r] + bb);
        *reinterpret_cast<us4*>(&Vf[base]) = pk;
      }
    }
  }
}

// Output projection v21: BM=128, BN=64, BK=64; 512 threads = 8 waves (4x2),
// wave tile 32x32. A via glds; B staged DIRECTLY from f32 wo (reg convert,
// T14 issue-early/write-late) — removes the cvt_w pass.
__global__ __launch_bounds__(512, 4)
void gemm_out(const unsigned short* __restrict__ A, const float* __restrict__ Bwf,
              const float* __restrict__ bias, float* __restrict__ Out) {
  constexpr int K = 1024, N = 1024;
  __shared__ __align__(16) unsigned short As[2][128 * 64];
  __shared__ __align__(16) unsigned short Bs[2][64 * 64];
  const int lid = blockIdx.x + (blockIdx.y << 5);
  const int xcd = lid & 7, slot = lid >> 3;
  const int chunk = ((slot >> 5) << 3) + xcd;
  const int pos = slot & 31;
  const int bm = ((chunk << 1) + (pos >> 4)) * 128;
  const int bn = (pos & 15) * 64;
  const int t = threadIdx.x;
  const int w = t >> 6, lane = t & 63, lr = lane & 15, lg = lane >> 4;
  const int wr = w >> 1, wc = w & 1;  // 4x2 wave grid
  const int swzc = (lr & 7) << 4;
  const int brow = t >> 3, bcol = (t & 7) * 8, bcb = (t & 7) * 16;

  f32x4 acc[2][2];
#pragma unroll
  for (int m = 0; m < 2; ++m)
#pragma unroll
    for (int n = 0; n < 2; ++n) acc[m][n] = f32x4{0.f, 0.f, 0.f, 0.f};

  auto stageA = [&](int k0, int buf) {
#pragma unroll
    for (int it = 0; it < 2; ++it) {
      const int s = it * 512 + t, row = s >> 3, cb = (s & 7) * 16;
      const char* g = (const char*)A + ((size_t)(bm + row) * 1024 + k0) * 2 +
                      (cb ^ ((row & 7) << 4));
      char* l = (char*)&As[buf][0] + (it * 512 + w * 64) * 16;
      glds16(g, l);
    }
  };
  float4 fb[2];
  auto loadB = [&](int k0) {
    const float4* p =
        reinterpret_cast<const float4*>(Bwf + (size_t)(bn + brow) * 1024 + k0 + bcol);
    fb[0] = p[0];
    fb[1] = p[1];
  };
  auto writeB = [&](int buf) {
    *reinterpret_cast<us8*>((char*)&Bs[buf][0] + brow * 128 +
                            (bcb ^ ((brow & 7) << 4))) = cvt8(fb[0], fb[1]);
  };

  stageA(0, 0);
  loadB(0);
  writeB(0);
  __syncthreads();

  for (int c = 0; c < 16; ++c) {
    const int buf = c & 1;
    if (c < 15) {
      const int k1 = (c + 1) * 64;
      stageA(k1, buf ^ 1);
      loadB(k1);  // T14: issue before compute
    }
#pragma unroll
    for (int h2 = 0; h2 < 2; ++h2) {
      bf16x8 af[2], bfr[2];
#pragma unroll
      for (int m = 0; m < 2; ++m) {
        const int row = wr * 32 + m * 16 + lr;
        af[m] = ldbf8((const unsigned short*)((char*)&As[buf][0] + row * 128 +
                                              ((h2 * 64 + lg * 16) ^ swzc)));
      }
#pragma unroll
      for (int n = 0; n < 2; ++n) {
        const int row = wc * 32 + n * 16 + lr;
        bfr[n] = ldbf8((const unsigned short*)((char*)&Bs[buf][0] + row * 128 +
                                               ((h2 * 64 + lg * 16) ^ swzc)));
      }
#pragma unroll
      for (int m = 0; m < 2; ++m)
#pragma unroll
        for (int n = 0; n < 2; ++n) acc[m][n] = MFMA(af[m], bfr[n], acc[m][n]);
    }
    if (c < 15) writeB(buf ^ 1);  // write-late convert
    __syncthreads();
  }

#pragma unroll
  for (int m = 0; m < 2; ++m) {
    const int mr = bm + wr * 32 + m * 16 + lg * 4;
#pragma unroll
    for (int nt = 0; nt < 2; ++nt) {
      const int n = bn + wc * 32 + nt * 16 + lr;
      const float bb = bias[n];
#pragma unroll
      for (int r = 0; r < 4; ++r) Out[(size_t)(mr + r) * N + n] = acc[m][nt][r] + bb;
    }
  }
}

// Flash attention v11: attn_v7 with the l-reduction hoisted out of the chunk
// loop (per-lane accumulate; single 2-shfl reduce in epilogue). WG-shared K/V
// glds staging (dbuf), fixed-offset softmax via Mf, cvt_pk P-pack, setprio.
__global__ __launch_bounds__(256)
void attn_v11(const unsigned short* __restrict__ Qb,
              const unsigned short* __restrict__ Kf,
              const unsigned short* __restrict__ Vf,
              const unsigned short* __restrict__ Mf,
              unsigned short* __restrict__ ctx) {
  __shared__ __align__(16) unsigned short S[2][8192];
  __shared__ __align__(16) unsigned short sP[4][16 * 64];
  const int lid = blockIdx.x + (blockIdx.y << 6);
  const int xcd = lid & 7, slot = lid >> 3;
  const int bh = ((slot >> 4) << 3) + xcd;
  const int qb = slot & 15;
  const int b = bh >> 4, h = bh & 15;
  const int t = threadIdx.x, w = t >> 6, wl = t & 63, lr = wl & 15, lg = wl >> 4;
  const int q0 = qb * 64 + w * 16;
  const int swz = (lr & 7) << 4;

  const unsigned short* qp = Qb + (size_t)(b * 1024 + q0 + lr) * 1024 + h * 64 + lg * 8;
  const bf16x8 bq0 = ldbf8(qp);
  const bf16x8 bq1 = ldbf8(qp + 32);

  const unsigned short* KfB = Kf + (size_t)bh * 65536;
  const unsigned short* VfB = Vf + (size_t)bh * 65536;
  const unsigned short* mfp = Mf + (size_t)((b * 64 + qb * 4 + w) * 64) * 256 + wl * 4;

  f32x4 O[4];
  float l_ = 0.f;  // per-lane partial; cross-lane reduced once at the end
#pragma unroll
  for (int dt = 0; dt < 4; ++dt) O[dt] = f32x4{0.f, 0.f, 0.f, 0.f};
  unsigned short* sp = &sP[w][0];

  auto stage = [&](int kc, int buf) {
    const unsigned short* srcs[4] = {KfB + kc * 2048, KfB + 32768 + kc * 2048,
                                     VfB + kc * 4096, VfB + kc * 4096 + 2048};
#pragma unroll
    for (int r = 0; r < 4; ++r) {
      const char* g = (const char*)(srcs[r] + (size_t)t * 8);
      char* l = (char*)&S[buf][r * 2048 + w * 512];
      glds16(g, l);
    }
  };

  stage(0, 0);
  __syncthreads();

  for (int kc = 0; kc < 16; ++kc) {
    const int buf = kc & 1;
    if (kc < 15) stage(kc + 1, buf ^ 1);

    us4 mk[4];
#pragma unroll
    for (int t4 = 0; t4 < 4; ++t4)
      mk[t4] = *reinterpret_cast<const us4*>(mfp + (size_t)(kc * 4 + t4) * 256);

    bf16x8 ak[4][2];
#pragma unroll
    for (int t4 = 0; t4 < 4; ++t4) {
      ak[t4][0] = ldbf8(&S[buf][t4 * 512 + wl * 8]);
      ak[t4][1] = ldbf8(&S[buf][2048 + t4 * 512 + wl * 8]);
    }

    f32x4 sc[4];
    __builtin_amdgcn_s_setprio(1);
#pragma unroll
    for (int t4 = 0; t4 < 4; ++t4) {
      f32x4 a;
#pragma unroll
      for (int r = 0; r < 4; ++r) a[r] = b2f(mk[t4][r]);
      a = MFMA(ak[t4][0], bq0, a);
      a = MFMA(ak[t4][1], bq1, a);
      sc[t4] = a;
    }
    __builtin_amdgcn_s_setprio(0);

#pragma unroll
    for (int t4 = 0; t4 < 4; ++t4) {
      const float e0 = EXP2(sc[t4][0]), e1 = EXP2(sc[t4][1]);
      const float e2 = EXP2(sc[t4][2]), e3 = EXP2(sc[t4][3]);
      l_ += (e0 + e1) + (e2 + e3);
      uint2 pw;
      pw.x = cvtpk(e0, e1);
      pw.y = cvtpk(e2, e3);
      *reinterpret_cast<uint2*>((char*)sp + lr * 128 + ((t4 * 32 + lg * 8) ^ swz)) = pw;
    }

    __builtin_amdgcn_s_setprio(1);
#pragma unroll
    for (int ks = 0; ks < 2; ++ks) {
      bf16x8 ap =
          ldbf8((const unsigned short*)((char*)sp + lr * 128 + ((ks * 64 + lg * 16) ^ swz)));
#pragma unroll
      for (int dt = 0; dt < 4; ++dt) {
        bf16x8 bv = ldbf8(&S[buf][4096 + ks * 2048 + dt * 512 + wl * 8]);
        O[dt] = MFMA(ap, bv, O[dt]);
      }
    }
    __builtin_amdgcn_s_setprio(0);

    __syncthreads();
  }

  // single cross-lane reduction (sum over lanes sharing lr)
  l_ += __shfl_xor(l_, 16);
  l_ += __shfl_xor(l_, 32);

  float linv[4];
#pragma unroll
  for (int r = 0; r < 4; ++r) linv[r] = 1.0f / __shfl(l_, lg * 4 + r);
#pragma unroll
  for (int dt = 0; dt < 4; ++dt)
#pragma unroll
    for (int r = 0; r < 4; ++r)
      ctx[(size_t)(b * 1024 + q0 + lg * 4 + r) * 1024 + h * 64 + dt * 16 + lr] =
          f2b(O[dt][r] * linv[r]);
}

extern "C" void kernel_launch(void* const* d_in, const int* in_sizes, int n_in,
                              void* d_out, int out_size, void* d_ws, size_t ws_size,
                              hipStream_t stream) {
  const float* query = (const float*)d_in[0];
  const float* key   = (const float*)d_in[1];
  const float* value = (const float*)d_in[2];
  const int*   mask  = (const int*)d_in[3];
  const float* wq = (const float*)d_in[4];
  const float* bq = (const float*)d_in[5];
  const float* wk = (const float*)d_in[6];
  const float* bk = (const float*)d_in[7];
  const float* wv = (const float*)d_in[8];
  const float* bv = (const float*)d_in[9];
  const float* wo = (const float*)d_in[10];
  const float* bo = (const float*)d_in[11];
  float* out = (float*)d_out;

  // ws [0..32MB): Qb, Kf, Vf, ctx (bf16, 8MB each). ctx slot doubles as Abfk
  // during the projection. d_out: Abfq [0..8M) then Mf overlays it; Wb [8..14M).
  // Abfv at ws+32MB only if ws_size >= 40MB. gemm_out reads wo (f32) directly.
  const size_t SZ = (size_t)4096 * 1024;
  unsigned short* Qb   = (unsigned short*)d_ws;
  unsigned short* Kf   = Qb + SZ;
  unsigned short* Vf   = Kf + SZ;
  unsigned short* ctx  = Vf + SZ;
  unsigned short* Abfq = (unsigned short*)d_out;
  unsigned short* Wb   = Abfq + SZ;
  unsigned short* Mf   = (unsigned short*)d_out;  // after projection
  unsigned short* Abfk = ctx;                     // before attn
  const bool big = ws_size >= (size_t)40 * 1024 * 1024;
  unsigned short* Abfv = big ? (ctx + SZ) : nullptr;  // ws+32MB

  const float qscale = 0.125f * 1.4426950408889634f;  // 1/sqrt(64) * log2(e)
  dim3 blk(256);
  prep<<<big ? 7680 : 5632, blk, 0, stream>>>(query, key, value, wq, wk, wv,
                                              Abfq, Abfk, Abfv, Wb);
  gemm_proj<<<dim3(32, 8, 3), dim3(512), 0, stream>>>(Abfq, Abfk, Abfv, value, Wb,
                                                      bq, bk, bv, Qb, Kf, Vf, qscale);
  maskcvt<<<4096, blk, 0, stream>>>(mask, Mf);
  attn_v11<<<dim3(64, 16), blk, 0, stream>>>(Qb, Kf, Vf, Mf, ctx);
  gemm_out<<<dim3(32, 16), dim3(512), 0, stream>>>(ctx, wo, bo, out);
}

// Round 22
// 113.965 us; speedup vs baseline: 1.0171x; 1.0050x over previous
//
#include <hip/hip_runtime.h>
#include <hip/hip_bf16.h>

// MHA forward: B=4, S=1024, D=1024, H=16, DK=64.
// v22: R21 base. gemm_proj converted to TRUE counted-vmcnt pipeline (T3/T4):
// 3 staging buffers (48KB, free — grid already caps at 3 WG/CU), raw s_barrier
// + s_waitcnt vmcnt(2) (never full drain in main loop); glds for tile c+2
// spans two compute phases. attn_v11 / gemm_out / prep / maskcvt unchanged.

typedef __bf16 bf16x8 __attribute__((ext_vector_type(8)));
typedef float f32x4 __attribute__((ext_vector_type(4)));
typedef unsigned short us8 __attribute__((ext_vector_type(8)));
typedef unsigned short us4 __attribute__((ext_vector_type(4)));

#define MFMA(a, b, c) __builtin_amdgcn_mfma_f32_16x16x32_bf16(a, b, c, 0, 0, 0)
#define EXP2(x) __builtin_amdgcn_exp2f(x)

__device__ __forceinline__ unsigned short f2b(float f) {
  return __builtin_bit_cast(unsigned short, __float2bfloat16(f));
}
__device__ __forceinline__ float b2f(unsigned short u) {
  return __builtin_bit_cast(float, (unsigned)u << 16);
}
__device__ __forceinline__ unsigned cvtpk(float lo, float hi) {
  unsigned r;
  asm("v_cvt_pk_bf16_f32 %0, %1, %2" : "=v"(r) : "v"(lo), "v"(hi));
  return r;
}
__device__ __forceinline__ bf16x8 ldbf8(const unsigned short* p) {
  return __builtin_bit_cast(bf16x8, *reinterpret_cast<const us8*>(p));
}
__device__ __forceinline__ us8 cvt8(float4 a, float4 b) {
  us8 o;
  o[0] = f2b(a.x); o[1] = f2b(a.y); o[2] = f2b(a.z); o[3] = f2b(a.w);
  o[4] = f2b(b.x); o[5] = f2b(b.y); o[6] = f2b(b.z); o[7] = f2b(b.w);
  return o;
}
__device__ __forceinline__ void glds16(const void* g, void* l) {
  __builtin_amdgcn_global_load_lds(
      (const __attribute__((address_space(1))) unsigned int*)g,
      (__attribute__((address_space(3))) unsigned int*)l, 16, 0, 0);
}

// prep: bid [0,1536): wq/wk/wv f32->bf16 -> Wb (3 x 1M elems, row-major).
//       bid [1536,3584): query -> Abfq; [3584,5632): key -> Abfk;
//       bid [5632,7680): value -> Abfv (launched only when ws is big enough).
__global__ __launch_bounds__(256)
void prep(const float* __restrict__ query, const float* __restrict__ key,
          const float* __restrict__ value, const float* __restrict__ wq,
          const float* __restrict__ wk, const float* __restrict__ wv,
          unsigned short* __restrict__ Abfq, unsigned short* __restrict__ Abfk,
          unsigned short* __restrict__ Abfv, unsigned short* __restrict__ Wb) {
  const int bid = blockIdx.x, tid = threadIdx.x;
  const float* src;
  unsigned short* dst;
  size_t off;
  if (bid < 1536) {
    const int widx = bid >> 9;
    src = (widx == 0) ? wq : (widx == 1) ? wk : wv;
    dst = Wb + (size_t)widx * 1048576;
    off = (size_t)(bid & 511) * 2048 + tid * 8;
  } else if (bid < 3584) {
    src = query; dst = Abfq; off = (size_t)(bid - 1536) * 2048 + tid * 8;
  } else if (bid < 5632) {
    src = key; dst = Abfk; off = (size_t)(bid - 3584) * 2048 + tid * 8;
  } else {
    src = value; dst = Abfv; off = (size_t)(bid - 5632) * 2048 + tid * 8;
  }
  const float4* p = reinterpret_cast<const float4*>(src + off);
  *reinterpret_cast<us8*>(dst + off) = cvt8(p[0], p[1]);
}

// mask[b][q][k] -> Mf in swapped QK^T C-frag order (C[k][q], q=lane&15).
// Fixed-offset softmax: unmasked = bf16(-24), masked = bf16(-1.44e9) = 0xCEAC.
__global__ __launch_bounds__(256)
void maskcvt(const int* __restrict__ mask, unsigned short* __restrict__ Mf) {
  const int idx = blockIdx.x * 256 + threadIdx.x;
  const int wl = idx & 63, tile = idx >> 6;
  const int kt = tile & 63, qt = (tile >> 6) & 63, b = tile >> 12;
  const int lr = wl & 15, lg = wl >> 4;
  const int4 mv = *reinterpret_cast<const int4*>(
      mask + (size_t)(b * 1024 + qt * 16 + lr) * 1024 + kt * 16 + lg * 4);
  us4 o;
  o[0] = mv.x ? 0xCEACu : 0xC1C0u;
  o[1] = mv.y ? 0xCEACu : 0xC1C0u;
  o[2] = mv.z ? 0xCEACu : 0xC1C0u;
  o[3] = mv.w ? 0xCEACu : 0xC1C0u;
  *reinterpret_cast<us4*>(Mf + (size_t)idx * 4) = o;
}

// Projection GEMM v22: BM=128, BN=128, BK=32; 512 threads = 8 waves (2x4);
// THREE staging buffers (48KB), counted-vmcnt pipeline: per iter each wave
// issues 2 glds (A+B for tile c+2); s_waitcnt vmcnt(2) + s_barrier certify
// tile c before compute. Conflict-free row-pair-interleaved LDS layout (v18).
// f32path (z==2 fallback when Av_bf==nullptr) keeps the old 2-buf sync loop.
__global__ __launch_bounds__(512, 6)
void gemm_proj(const unsigned short* __restrict__ Aq,
               const unsigned short* __restrict__ Ak,
               const unsigned short* __restrict__ Av_bf,
               const float* __restrict__ Av_f32,
               const unsigned short* __restrict__ Wb,
               const float* __restrict__ bq, const float* __restrict__ bk,
               const float* __restrict__ bv, unsigned short* __restrict__ Qb,
               unsigned short* __restrict__ Kf, unsigned short* __restrict__ Vf,
               float qscale) {
  constexpr int K = 1024, N = 1024;
  __shared__ __align__(16) unsigned short As[3][128 * 32];  // 8KB each
  __shared__ __align__(16) unsigned short Bs[3][128 * 32];
  const int lid = blockIdx.x + (blockIdx.y << 5) + (blockIdx.z << 8);
  const int xcd = lid & 7, slot = lid >> 3;
  const int chunk = ((slot >> 3) << 3) + xcd;
  const int z = chunk >> 5;
  const int bm = (chunk & 31) * 128;
  const int bn = (slot & 7) * 128;

  const unsigned short* Abf = (z == 0) ? Aq : (z == 1) ? Ak : Av_bf;
  const bool f32path = (z == 2) && (Av_bf == nullptr);
  const unsigned short* Bw = Wb + (size_t)z * 1048576;
  const float* bias = (z == 0) ? bq : (z == 1) ? bk : bv;
  const int t = threadIdx.x;
  const int w = t >> 6, lane = t & 63, lr = lane & 15, lg = lane >> 4;
  const int wr = w >> 2, wc = w & 3;

  const int sline = t >> 3;
  const int su = (t & 7) ^ (sline & 7);
  const int srow = sline * 2 + (su >> 2);
  const int scol = (su & 3) * 8;

  f32x4 acc[4][2];
#pragma unroll
  for (int m = 0; m < 4; ++m)
#pragma unroll
    for (int n = 0; n < 2; ++n) acc[m][n] = f32x4{0.f, 0.f, 0.f, 0.f};

  auto stageA = [&](int k0, int buf) {
    const char* g = (const char*)(Abf + (size_t)(bm + srow) * 1024 + k0 + scol);
    char* l = (char*)&As[buf][0] + (w * 64) * 16;
    glds16(g, l);
  };
  auto stageB = [&](int k0, int buf) {
    const char* g = (const char*)(Bw + (size_t)(bn + srow) * 1024 + k0 + scol);
    char* l = (char*)&Bs[buf][0] + (w * 64) * 16;
    glds16(g, l);
  };
#define STA8(buf, v)                                                           \
  { *reinterpret_cast<us8*>((char*)&As[buf][0] + t * 16) = (v); }
#define RDOFF(row) (((row) >> 1) * 128 +                                       \
                    (((lg | (((row) & 1) << 2)) ^ (((row) >> 1) & 7)) * 16))
#define COMPUTE(buf)                                                           \
  {                                                                            \
    bf16x8 af[4], bfr[2];                                                      \
    _Pragma("unroll") for (int m = 0; m < 4; ++m) {                            \
      const int row = wr * 64 + m * 16 + lr;                                   \
      af[m] = ldbf8((const unsigned short*)((char*)&As[buf][0] + RDOFF(row))); \
    }                                                                          \
    _Pragma("unroll") for (int n = 0; n < 2; ++n) {                            \
      const int row = wc * 32 + n * 16 + lr;                                   \
      bfr[n] = ldbf8((const unsigned short*)((char*)&Bs[buf][0] + RDOFF(row)));\
    }                                                                          \
    _Pragma("unroll") for (int m = 0; m < 4; ++m)                              \
        _Pragma("unroll") for (int n = 0; n < 2; ++n)                          \
        acc[m][n] = MFMA(af[m], bfr[n], acc[m][n]);                            \
  }

  if (!f32path) {
    // ---- counted-vmcnt 3-buffer pipeline ----
    stageA(0, 0);
    stageB(0, 0);
    stageA(32, 1);
    stageB(32, 1);
    for (int c = 0; c < 32; ++c) {
      const int buf = c % 3;
      // certify this wave's tile-c loads (2 newer stages may stay in flight)
      if (c < 31) {
        asm volatile("s_waitcnt vmcnt(4)" ::: "memory");  // placeholder, fixed below
      }
      // NOTE: counts — at top of iter c the wave has stage(c)+stage(c+1)
      // outstanding (4 loads) except at c=31 (only stage(31), 2 loads).
      if (c < 31) {
        asm volatile("s_waitcnt vmcnt(2)" ::: "memory");
      } else {
        asm volatile("s_waitcnt vmcnt(0)" ::: "memory");
      }
      __builtin_amdgcn_s_barrier();  // all waves: tile-c landed, prev reads done
      if (c < 30) {
        const int nb = (c + 2) % 3;
        stageA((c + 2) * 32, nb);
        stageB((c + 2) * 32, nb);
      }
      COMPUTE(buf)
    }
  } else {
    // ---- legacy 2-buffer __syncthreads loop (reg-staged f32 A) ----
    {
      const float4* p =
          reinterpret_cast<const float4*>(Av_f32 + (size_t)(bm + srow) * K + scol);
      STA8(0, cvt8(p[0], p[1]));
      stageB(0, 0);
    }
    __syncthreads();
    for (int c = 0; c < 32; ++c) {
      const int buf = c & 1;
      float4 fa[2];
      if (c < 31) {
        const int k1 = (c + 1) * 32;
        const float4* p = reinterpret_cast<const float4*>(
            Av_f32 + (size_t)(bm + srow) * K + k1 + scol);
        fa[0] = p[0];
        fa[1] = p[1];
        stageB(k1, buf ^ 1);
      }
      COMPUTE(buf)
      if (c < 31) {
        STA8(buf ^ 1, cvt8(fa[0], fa[1]));
      }
      __syncthreads();
    }
  }
#undef STA8
#undef RDOFF
#undef COMPUTE

#pragma unroll
  for (int m = 0; m < 4; ++m) {
    const int mr = bm + wr * 64 + m * 16 + lg * 4;
#pragma unroll
    for (int nt = 0; nt < 2; ++nt) {
      const int n = bn + wc * 32 + nt * 16 + lr;
      const float bb = bias[n];
      if (z == 0) {
#pragma unroll
        for (int r = 0; r < 4; ++r)
          Qb[(size_t)(mr + r) * N + n] = f2b((acc[m][nt][r] + bb) * qscale);
      } else if (z == 1) {
        // Kf: K[bh][s][d] -> bh*65536 + (d>>5)*32768 + (s>>4)*512
        //     + ((s&15)|(((d>>3)&3)<<4))*8 + (d&7)
        const int b2 = mr >> 10, s0 = mr & 1023, hh = n >> 6, dd = n & 63;
        const size_t base = (size_t)(b2 * 16 + hh) * 65536 + (size_t)(dd >> 5) * 32768 +
                            (size_t)(s0 >> 4) * 512 +
                            (size_t)((s0 & 15) | (((dd >> 3) & 3) << 4)) * 8 + (dd & 7);
#pragma unroll
        for (int r = 0; r < 4; ++r) Kf[base + r * 8] = f2b(acc[m][nt][r] + bb);
      } else {
        // Vf: V[bh][s][d] -> bh*65536 + (s>>5)*2048 + (d>>4)*512
        //     + ((d&15)|(((s>>3)&3)<<4))*8 + (s&7)
        const int b2 = mr >> 10, s0 = mr & 1023, hh = n >> 6, dd = n & 63;
        const size_t base = (size_t)(b2 * 16 + hh) * 65536 + (size_t)(s0 >> 5) * 2048 +
                            (size_t)(dd >> 4) * 512 +
                            (size_t)((dd & 15) | (((s0 >> 3) & 3) << 4)) * 8 + (s0 & 7);
        us4 pk;
#pragma unroll
        for (int r = 0; r < 4; ++r) pk[r] = f2b(acc[m][nt][r] + bb);
        *reinterpret_cast<us4*>(&Vf[base]) = pk;
      }
    }
  }
}

// Output projection v21 (unchanged): BM=128, BN=64, BK=64; 512 threads; A via
// glds, B staged directly from f32 wo (reg convert, T14 split).
__global__ __launch_bounds__(512, 4)
void gemm_out(const unsigned short* __restrict__ A, const float* __restrict__ Bwf,
              const float* __restrict__ bias, float* __restrict__ Out) {
  constexpr int K = 1024, N = 1024;
  __shared__ __align__(16) unsigned short As[2][128 * 64];
  __shared__ __align__(16) unsigned short Bs[2][64 * 64];
  const int lid = blockIdx.x + (blockIdx.y << 5);
  const int xcd = lid & 7, slot = lid >> 3;
  const int chunk = ((slot >> 5) << 3) + xcd;
  const int pos = slot & 31;
  const int bm = ((chunk << 1) + (pos >> 4)) * 128;
  const int bn = (pos & 15) * 64;
  const int t = threadIdx.x;
  const int w = t >> 6, lane = t & 63, lr = lane & 15, lg = lane >> 4;
  const int wr = w >> 1, wc = w & 1;
  const int swzc = (lr & 7) << 4;
  const int brow = t >> 3, bcol = (t & 7) * 8, bcb = (t & 7) * 16;

  f32x4 acc[2][2];
#pragma unroll
  for (int m = 0; m < 2; ++m)
#pragma unroll
    for (int n = 0; n < 2; ++n) acc[m][n] = f32x4{0.f, 0.f, 0.f, 0.f};

  auto stageA = [&](int k0, int buf) {
#pragma unroll
    for (int it = 0; it < 2; ++it) {
      const int s = it * 512 + t, row = s >> 3, cb = (s & 7) * 16;
      const char* g = (const char*)A + ((size_t)(bm + row) * 1024 + k0) * 2 +
                      (cb ^ ((row & 7) << 4));
      char* l = (char*)&As[buf][0] + (it * 512 + w * 64) * 16;
      glds16(g, l);
    }
  };
  float4 fb[2];
  auto loadB = [&](int k0) {
    const float4* p =
        reinterpret_cast<const float4*>(Bwf + (size_t)(bn + brow) * 1024 + k0 + bcol);
    fb[0] = p[0];
    fb[1] = p[1];
  };
  auto writeB = [&](int buf) {
    *reinterpret_cast<us8*>((char*)&Bs[buf][0] + brow * 128 +
                            (bcb ^ ((brow & 7) << 4))) = cvt8(fb[0], fb[1]);
  };

  stageA(0, 0);
  loadB(0);
  writeB(0);
  __syncthreads();

  for (int c = 0; c < 16; ++c) {
    const int buf = c & 1;
    if (c < 15) {
      const int k1 = (c + 1) * 64;
      stageA(k1, buf ^ 1);
      loadB(k1);
    }
#pragma unroll
    for (int h2 = 0; h2 < 2; ++h2) {
      bf16x8 af[2], bfr[2];
#pragma unroll
      for (int m = 0; m < 2; ++m) {
        const int row = wr * 32 + m * 16 + lr;
        af[m] = ldbf8((const unsigned short*)((char*)&As[buf][0] + row * 128 +
                                              ((h2 * 64 + lg * 16) ^ swzc)));
      }
#pragma unroll
      for (int n = 0; n < 2; ++n) {
        const int row = wc * 32 + n * 16 + lr;
        bfr[n] = ldbf8((const unsigned short*)((char*)&Bs[buf][0] + row * 128 +
                                               ((h2 * 64 + lg * 16) ^ swzc)));
      }
#pragma unroll
      for (int m = 0; m < 2; ++m)
#pragma unroll
        for (int n = 0; n < 2; ++n) acc[m][n] = MFMA(af[m], bfr[n], acc[m][n]);
    }
    if (c < 15) writeB(buf ^ 1);
    __syncthreads();
  }

#pragma unroll
  for (int m = 0; m < 2; ++m) {
    const int mr = bm + wr * 32 + m * 16 + lg * 4;
#pragma unroll
    for (int nt = 0; nt < 2; ++nt) {
      const int n = bn + wc * 32 + nt * 16 + lr;
      const float bb = bias[n];
#pragma unroll
      for (int r = 0; r < 4; ++r) Out[(size_t)(mr + r) * N + n] = acc[m][nt][r] + bb;
    }
  }
}

// Flash attention v11 (unchanged): WG-shared K/V glds staging (dbuf),
// fixed-offset softmax via Mf, cvt_pk P-pack, setprio, hoisted l-reduction.
__global__ __launch_bounds__(256)
void attn_v11(const unsigned short* __restrict__ Qb,
              const unsigned short* __restrict__ Kf,
              const unsigned short* __restrict__ Vf,
              const unsigned short* __restrict__ Mf,
              unsigned short* __restrict__ ctx) {
  __shared__ __align__(16) unsigned short S[2][8192];
  __shared__ __align__(16) unsigned short sP[4][16 * 64];
  const int lid = blockIdx.x + (blockIdx.y << 6);
  const int xcd = lid & 7, slot = lid >> 3;
  const int bh = ((slot >> 4) << 3) + xcd;
  const int qb = slot & 15;
  const int b = bh >> 4, h = bh & 15;
  const int t = threadIdx.x, w = t >> 6, wl = t & 63, lr = wl & 15, lg = wl >> 4;
  const int q0 = qb * 64 + w * 16;
  const int swz = (lr & 7) << 4;

  const unsigned short* qp = Qb + (size_t)(b * 1024 + q0 + lr) * 1024 + h * 64 + lg * 8;
  const bf16x8 bq0 = ldbf8(qp);
  const bf16x8 bq1 = ldbf8(qp + 32);

  const unsigned short* KfB = Kf + (size_t)bh * 65536;
  const unsigned short* VfB = Vf + (size_t)bh * 65536;
  const unsigned short* mfp = Mf + (size_t)((b * 64 + qb * 4 + w) * 64) * 256 + wl * 4;

  f32x4 O[4];
  float l_ = 0.f;
#pragma unroll
  for (int dt = 0; dt < 4; ++dt) O[dt] = f32x4{0.f, 0.f, 0.f, 0.f};
  unsigned short* sp = &sP[w][0];

  auto stage = [&](int kc, int buf) {
    const unsigned short* srcs[4] = {KfB + kc * 2048, KfB + 32768 + kc * 2048,
                                     VfB + kc * 4096, VfB + kc * 4096 + 2048};
#pragma unroll
    for (int r = 0; r < 4; ++r) {
      const char* g = (const char*)(srcs[r] + (size_t)t * 8);
      char* l = (char*)&S[buf][r * 2048 + w * 512];
      glds16(g, l);
    }
  };

  stage(0, 0);
  __syncthreads();

  for (int kc = 0; kc < 16; ++kc) {
    const int buf = kc & 1;
    if (kc < 15) stage(kc + 1, buf ^ 1);

    us4 mk[4];
#pragma unroll
    for (int t4 = 0; t4 < 4; ++t4)
      mk[t4] = *reinterpret_cast<const us4*>(mfp + (size_t)(kc * 4 + t4) * 256);

    bf16x8 ak[4][2];
#pragma unroll
    for (int t4 = 0; t4 < 4; ++t4) {
      ak[t4][0] = ldbf8(&S[buf][t4 * 512 + wl * 8]);
      ak[t4][1] = ldbf8(&S[buf][2048 + t4 * 512 + wl * 8]);
    }

    f32x4 sc[4];
    __builtin_amdgcn_s_setprio(1);
#pragma unroll
    for (int t4 = 0; t4 < 4; ++t4) {
      f32x4 a;
#pragma unroll
      for (int r = 0; r < 4; ++r) a[r] = b2f(mk[t4][r]);
      a = MFMA(ak[t4][0], bq0, a);
      a = MFMA(ak[t4][1], bq1, a);
      sc[t4] = a;
    }
    __builtin_amdgcn_s_setprio(0);

#pragma unroll
    for (int t4 = 0; t4 < 4; ++t4) {
      const float e0 = EXP2(sc[t4][0]), e1 = EXP2(sc[t4][1]);
      const float e2 = EXP2(sc[t4][2]), e3 = EXP2(sc[t4][3]);
      l_ += (e0 + e1) + (e2 + e3);
      uint2 pw;
      pw.x = cvtpk(e0, e1);
      pw.y = cvtpk(e2, e3);
      *reinterpret_cast<uint2*>((char*)sp + lr * 128 + ((t4 * 32 + lg * 8) ^ swz)) = pw;
    }

    __builtin_amdgcn_s_setprio(1);
#pragma unroll
    for (int ks = 0; ks < 2; ++ks) {
      bf16x8 ap =
          ldbf8((const unsigned short*)((char*)sp + lr * 128 + ((ks * 64 + lg * 16) ^ swz)));
#pragma unroll
      for (int dt = 0; dt < 4; ++dt) {
        bf16x8 bv = ldbf8(&S[buf][4096 + ks * 2048 + dt * 512 + wl * 8]);
        O[dt] = MFMA(ap, bv, O[dt]);
      }
    }
    __builtin_amdgcn_s_setprio(0);

    __syncthreads();
  }

  l_ += __shfl_xor(l_, 16);
  l_ += __shfl_xor(l_, 32);

  float linv[4];
#pragma unroll
  for (int r = 0; r < 4; ++r) linv[r] = 1.0f / __shfl(l_, lg * 4 + r);
#pragma unroll
  for (int dt = 0; dt < 4; ++dt)
#pragma unroll
    for (int r = 0; r < 4; ++r)
      ctx[(size_t)(b * 1024 + q0 + lg * 4 + r) * 1024 + h * 64 + dt * 16 + lr] =
          f2b(O[dt][r] * linv[r]);
}

extern "C" void kernel_launch(void* const* d_in, const int* in_sizes, int n_in,
                              void* d_out, int out_size, void* d_ws, size_t ws_size,
                              hipStream_t stream) {
  const float* query = (const float*)d_in[0];
  const float* key   = (const float*)d_in[1];
  const float* value = (const float*)d_in[2];
  const int*   mask  = (const int*)d_in[3];
  const float* wq = (const float*)d_in[4];
  const float* bq = (const float*)d_in[5];
  const float* wk = (const float*)d_in[6];
  const float* bk = (const float*)d_in[7];
  const float* wv = (const float*)d_in[8];
  const float* bv = (const float*)d_in[9];
  const float* wo = (const float*)d_in[10];
  const float* bo = (const float*)d_in[11];
  float* out = (float*)d_out;

  // ws [0..32MB): Qb, Kf, Vf, ctx (bf16, 8MB each). ctx slot doubles as Abfk
  // during the projection. d_out: Abfq [0..8M) then Mf overlays it; Wb [8..14M).
  // Abfv at ws+32MB only if ws_size >= 40MB. gemm_out reads wo (f32) directly.
  const size_t SZ = (size_t)4096 * 1024;
  unsigned short* Qb   = (unsigned short*)d_ws;
  unsigned short* Kf   = Qb + SZ;
  unsigned short* Vf   = Kf + SZ;
  unsigned short* ctx  = Vf + SZ;
  unsigned short* Abfq = (unsigned short*)d_out;
  unsigned short* Wb   = Abfq + SZ;
  unsigned short* Mf   = (unsigned short*)d_out;  // after projection
  unsigned short* Abfk = ctx;                     // before attn
  const bool big = ws_size >= (size_t)40 * 1024 * 1024;
  unsigned short* Abfv = big ? (ctx + SZ) : nullptr;  // ws+32MB

  const float qscale = 0.125f * 1.4426950408889634f;  // 1/sqrt(64) * log2(e)
  dim3 blk(256);
  prep<<<big ? 7680 : 5632, blk, 0, stream>>>(query, key, value, wq, wk, wv,
                                              Abfq, Abfk, Abfv, Wb);
  gemm_proj<<<dim3(32, 8, 3), dim3(512), 0, stream>>>(Abfq, Abfk, Abfv, value, Wb,
                                                      bq, bk, bv, Qb, Kf, Vf, qscale);
  maskcvt<<<4096, blk, 0, stream>>>(mask, Mf);
  attn_v11<<<dim3(64, 16), blk, 0, stream>>>(Qb, Kf, Vf, Mf, ctx);
  gemm_out<<<dim3(32, 16), dim3(512), 0, stream>>>(ctx, wo, bo, out);
}

// Round 23
// 112.445 us; speedup vs baseline: 1.0309x; 1.0135x over previous
//
#include <hip/hip_runtime.h>
#include <hip/hip_bf16.h>

// MHA forward: B=4, S=1024, D=1024, H=16, DK=64.
// v23: R22 base (counted-vmcnt gemm_proj, best 114.0us) + Mf carried as int8
// (0/1) instead of bf16 — halves mask-bias traffic; attn C-init via cndmask.

typedef __bf16 bf16x8 __attribute__((ext_vector_type(8)));
typedef float f32x4 __attribute__((ext_vector_type(4)));
typedef unsigned short us8 __attribute__((ext_vector_type(8)));
typedef unsigned short us4 __attribute__((ext_vector_type(4)));

#define MFMA(a, b, c) __builtin_amdgcn_mfma_f32_16x16x32_bf16(a, b, c, 0, 0, 0)
#define EXP2(x) __builtin_amdgcn_exp2f(x)

__device__ __forceinline__ unsigned short f2b(float f) {
  return __builtin_bit_cast(unsigned short, __float2bfloat16(f));
}
__device__ __forceinline__ unsigned cvtpk(float lo, float hi) {
  unsigned r;
  asm("v_cvt_pk_bf16_f32 %0, %1, %2" : "=v"(r) : "v"(lo), "v"(hi));
  return r;
}
__device__ __forceinline__ bf16x8 ldbf8(const unsigned short* p) {
  return __builtin_bit_cast(bf16x8, *reinterpret_cast<const us8*>(p));
}
__device__ __forceinline__ us8 cvt8(float4 a, float4 b) {
  us8 o;
  o[0] = f2b(a.x); o[1] = f2b(a.y); o[2] = f2b(a.z); o[3] = f2b(a.w);
  o[4] = f2b(b.x); o[5] = f2b(b.y); o[6] = f2b(b.z); o[7] = f2b(b.w);
  return o;
}
__device__ __forceinline__ void glds16(const void* g, void* l) {
  __builtin_amdgcn_global_load_lds(
      (const __attribute__((address_space(1))) unsigned int*)g,
      (__attribute__((address_space(3))) unsigned int*)l, 16, 0, 0);
}

// prep: bid [0,1536): wq/wk/wv f32->bf16 -> Wb (3 x 1M elems, row-major).
//       bid [1536,3584): query -> Abfq; [3584,5632): key -> Abfk;
//       bid [5632,7680): value -> Abfv (launched only when ws is big enough).
__global__ __launch_bounds__(256)
void prep(const float* __restrict__ query, const float* __restrict__ key,
          const float* __restrict__ value, const float* __restrict__ wq,
          const float* __restrict__ wk, const float* __restrict__ wv,
          unsigned short* __restrict__ Abfq, unsigned short* __restrict__ Abfk,
          unsigned short* __restrict__ Abfv, unsigned short* __restrict__ Wb) {
  const int bid = blockIdx.x, tid = threadIdx.x;
  const float* src;
  unsigned short* dst;
  size_t off;
  if (bid < 1536) {
    const int widx = bid >> 9;
    src = (widx == 0) ? wq : (widx == 1) ? wk : wv;
    dst = Wb + (size_t)widx * 1048576;
    off = (size_t)(bid & 511) * 2048 + tid * 8;
  } else if (bid < 3584) {
    src = query; dst = Abfq; off = (size_t)(bid - 1536) * 2048 + tid * 8;
  } else if (bid < 5632) {
    src = key; dst = Abfk; off = (size_t)(bid - 3584) * 2048 + tid * 8;
  } else {
    src = value; dst = Abfv; off = (size_t)(bid - 5632) * 2048 + tid * 8;
  }
  const float4* p = reinterpret_cast<const float4*>(src + off);
  *reinterpret_cast<us8*>(dst + off) = cvt8(p[0], p[1]);
}

// mask[b][q][k] -> Mf8 (int8 0/1) in swapped QK^T C-frag order (C[k][q]).
__global__ __launch_bounds__(256)
void maskcvt(const int* __restrict__ mask, unsigned char* __restrict__ Mf8) {
  const int idx = blockIdx.x * 256 + threadIdx.x;
  const int wl = idx & 63, tile = idx >> 6;
  const int kt = tile & 63, qt = (tile >> 6) & 63, b = tile >> 12;
  const int lr = wl & 15, lg = wl >> 4;
  const int4 mv = *reinterpret_cast<const int4*>(
      mask + (size_t)(b * 1024 + qt * 16 + lr) * 1024 + kt * 16 + lg * 4);
  uchar4 o;
  o.x = (unsigned char)(mv.x != 0);
  o.y = (unsigned char)(mv.y != 0);
  o.z = (unsigned char)(mv.z != 0);
  o.w = (unsigned char)(mv.w != 0);
  *reinterpret_cast<uchar4*>(Mf8 + (size_t)idx * 4) = o;
}

// Projection GEMM v22 (unchanged): BM=128, BN=128, BK=32; 512 threads; 3-buf
// counted-vmcnt pipeline; conflict-free row-pair-interleaved LDS layout.
__global__ __launch_bounds__(512, 6)
void gemm_proj(const unsigned short* __restrict__ Aq,
               const unsigned short* __restrict__ Ak,
               const unsigned short* __restrict__ Av_bf,
               const float* __restrict__ Av_f32,
               const unsigned short* __restrict__ Wb,
               const float* __restrict__ bq, const float* __restrict__ bk,
               const float* __restrict__ bv, unsigned short* __restrict__ Qb,
               unsigned short* __restrict__ Kf, unsigned short* __restrict__ Vf,
               float qscale) {
  constexpr int K = 1024, N = 1024;
  __shared__ __align__(16) unsigned short As[3][128 * 32];
  __shared__ __align__(16) unsigned short Bs[3][128 * 32];
  const int lid = blockIdx.x + (blockIdx.y << 5) + (blockIdx.z << 8);
  const int xcd = lid & 7, slot = lid >> 3;
  const int chunk = ((slot >> 3) << 3) + xcd;
  const int z = chunk >> 5;
  const int bm = (chunk & 31) * 128;
  const int bn = (slot & 7) * 128;

  const unsigned short* Abf = (z == 0) ? Aq : (z == 1) ? Ak : Av_bf;
  const bool f32path = (z == 2) && (Av_bf == nullptr);
  const unsigned short* Bw = Wb + (size_t)z * 1048576;
  const float* bias = (z == 0) ? bq : (z == 1) ? bk : bv;
  const int t = threadIdx.x;
  const int w = t >> 6, lane = t & 63, lr = lane & 15, lg = lane >> 4;
  const int wr = w >> 2, wc = w & 3;

  const int sline = t >> 3;
  const int su = (t & 7) ^ (sline & 7);
  const int srow = sline * 2 + (su >> 2);
  const int scol = (su & 3) * 8;

  f32x4 acc[4][2];
#pragma unroll
  for (int m = 0; m < 4; ++m)
#pragma unroll
    for (int n = 0; n < 2; ++n) acc[m][n] = f32x4{0.f, 0.f, 0.f, 0.f};

  auto stageA = [&](int k0, int buf) {
    const char* g = (const char*)(Abf + (size_t)(bm + srow) * 1024 + k0 + scol);
    char* l = (char*)&As[buf][0] + (w * 64) * 16;
    glds16(g, l);
  };
  auto stageB = [&](int k0, int buf) {
    const char* g = (const char*)(Bw + (size_t)(bn + srow) * 1024 + k0 + scol);
    char* l = (char*)&Bs[buf][0] + (w * 64) * 16;
    glds16(g, l);
  };
#define STA8(buf, v)                                                           \
  { *reinterpret_cast<us8*>((char*)&As[buf][0] + t * 16) = (v); }
#define RDOFF(row) (((row) >> 1) * 128 +                                       \
                    (((lg | (((row) & 1) << 2)) ^ (((row) >> 1) & 7)) * 16))
#define COMPUTE(buf)                                                           \
  {                                                                            \
    bf16x8 af[4], bfr[2];                                                      \
    _Pragma("unroll") for (int m = 0; m < 4; ++m) {                            \
      const int row = wr * 64 + m * 16 + lr;                                   \
      af[m] = ldbf8((const unsigned short*)((char*)&As[buf][0] + RDOFF(row))); \
    }                                                                          \
    _Pragma("unroll") for (int n = 0; n < 2; ++n) {                            \
      const int row = wc * 32 + n * 16 + lr;                                   \
      bfr[n] = ldbf8((const unsigned short*)((char*)&Bs[buf][0] + RDOFF(row)));\
    }                                                                          \
    _Pragma("unroll") for (int m = 0; m < 4; ++m)                              \
        _Pragma("unroll") for (int n = 0; n < 2; ++n)                          \
        acc[m][n] = MFMA(af[m], bfr[n], acc[m][n]);                            \
  }

  if (!f32path) {
    stageA(0, 0);
    stageB(0, 0);
    stageA(32, 1);
    stageB(32, 1);
    for (int c = 0; c < 32; ++c) {
      const int buf = c % 3;
      if (c < 31) {
        asm volatile("s_waitcnt vmcnt(2)" ::: "memory");
      } else {
        asm volatile("s_waitcnt vmcnt(0)" ::: "memory");
      }
      __builtin_amdgcn_s_barrier();
      if (c < 30) {
        const int nb = (c + 2) % 3;
        stageA((c + 2) * 32, nb);
        stageB((c + 2) * 32, nb);
      }
      COMPUTE(buf)
    }
  } else {
    {
      const float4* p =
          reinterpret_cast<const float4*>(Av_f32 + (size_t)(bm + srow) * K + scol);
      STA8(0, cvt8(p[0], p[1]));
      stageB(0, 0);
    }
    __syncthreads();
    for (int c = 0; c < 32; ++c) {
      const int buf = c & 1;
      float4 fa[2];
      if (c < 31) {
        const int k1 = (c + 1) * 32;
        const float4* p = reinterpret_cast<const float4*>(
            Av_f32 + (size_t)(bm + srow) * K + k1 + scol);
        fa[0] = p[0];
        fa[1] = p[1];
        stageB(k1, buf ^ 1);
      }
      COMPUTE(buf)
      if (c < 31) {
        STA8(buf ^ 1, cvt8(fa[0], fa[1]));
      }
      __syncthreads();
    }
  }
#undef STA8
#undef RDOFF
#undef COMPUTE

#pragma unroll
  for (int m = 0; m < 4; ++m) {
    const int mr = bm + wr * 64 + m * 16 + lg * 4;
#pragma unroll
    for (int nt = 0; nt < 2; ++nt) {
      const int n = bn + wc * 32 + nt * 16 + lr;
      const float bb = bias[n];
      if (z == 0) {
#pragma unroll
        for (int r = 0; r < 4; ++r)
          Qb[(size_t)(mr + r) * N + n] = f2b((acc[m][nt][r] + bb) * qscale);
      } else if (z == 1) {
        // Kf: K[bh][s][d] -> bh*65536 + (d>>5)*32768 + (s>>4)*512
        //     + ((s&15)|(((d>>3)&3)<<4))*8 + (d&7)
        const int b2 = mr >> 10, s0 = mr & 1023, hh = n >> 6, dd = n & 63;
        const size_t base = (size_t)(b2 * 16 + hh) * 65536 + (size_t)(dd >> 5) * 32768 +
                            (size_t)(s0 >> 4) * 512 +
                            (size_t)((s0 & 15) | (((dd >> 3) & 3) << 4)) * 8 + (dd & 7);
#pragma unroll
        for (int r = 0; r < 4; ++r) Kf[base + r * 8] = f2b(acc[m][nt][r] + bb);
      } else {
        // Vf: V[bh][s][d] -> bh*65536 + (s>>5)*2048 + (d>>4)*512
        //     + ((d&15)|(((s>>3)&3)<<4))*8 + (s&7)
        const int b2 = mr >> 10, s0 = mr & 1023, hh = n >> 6, dd = n & 63;
        const size_t base = (size_t)(b2 * 16 + hh) * 65536 + (size_t)(s0 >> 5) * 2048 +
                            (size_t)(dd >> 4) * 512 +
                            (size_t)((dd & 15) | (((s0 >> 3) & 3) << 4)) * 8 + (s0 & 7);
        us4 pk;
#pragma unroll
        for (int r = 0; r < 4; ++r) pk[r] = f2b(acc[m][nt][r] + bb);
        *reinterpret_cast<us4*>(&Vf[base]) = pk;
      }
    }
  }
}

// Output projection v21 (unchanged): BM=128, BN=64, BK=64; 512 threads; A via
// glds, B staged directly from f32 wo (reg convert, T14 split).
__global__ __launch_bounds__(512, 4)
void gemm_out(const unsigned short* __restrict__ A, const float* __restrict__ Bwf,
              const float* __restrict__ bias, float* __restrict__ Out) {
  constexpr int K = 1024, N = 1024;
  __shared__ __align__(16) unsigned short As[2][128 * 64];
  __shared__ __align__(16) unsigned short Bs[2][64 * 64];
  const int lid = blockIdx.x + (blockIdx.y << 5);
  const int xcd = lid & 7, slot = lid >> 3;
  const int chunk = ((slot >> 5) << 3) + xcd;
  const int pos = slot & 31;
  const int bm = ((chunk << 1) + (pos >> 4)) * 128;
  const int bn = (pos & 15) * 64;
  const int t = threadIdx.x;
  const int w = t >> 6, lane = t & 63, lr = lane & 15, lg = lane >> 4;
  const int wr = w >> 1, wc = w & 1;
  const int swzc = (lr & 7) << 4;
  const int brow = t >> 3, bcol = (t & 7) * 8, bcb = (t & 7) * 16;

  f32x4 acc[2][2];
#pragma unroll
  for (int m = 0; m < 2; ++m)
#pragma unroll
    for (int n = 0; n < 2; ++n) acc[m][n] = f32x4{0.f, 0.f, 0.f, 0.f};

  auto stageA = [&](int k0, int buf) {
#pragma unroll
    for (int it = 0; it < 2; ++it) {
      const int s = it * 512 + t, row = s >> 3, cb = (s & 7) * 16;
      const char* g = (const char*)A + ((size_t)(bm + row) * 1024 + k0) * 2 +
                      (cb ^ ((row & 7) << 4));
      char* l = (char*)&As[buf][0] + (it * 512 + w * 64) * 16;
      glds16(g, l);
    }
  };
  float4 fb[2];
  auto loadB = [&](int k0) {
    const float4* p =
        reinterpret_cast<const float4*>(Bwf + (size_t)(bn + brow) * 1024 + k0 + bcol);
    fb[0] = p[0];
    fb[1] = p[1];
  };
  auto writeB = [&](int buf) {
    *reinterpret_cast<us8*>((char*)&Bs[buf][0] + brow * 128 +
                            (bcb ^ ((brow & 7) << 4))) = cvt8(fb[0], fb[1]);
  };

  stageA(0, 0);
  loadB(0);
  writeB(0);
  __syncthreads();

  for (int c = 0; c < 16; ++c) {
    const int buf = c & 1;
    if (c < 15) {
      const int k1 = (c + 1) * 64;
      stageA(k1, buf ^ 1);
      loadB(k1);
    }
#pragma unroll
    for (int h2 = 0; h2 < 2; ++h2) {
      bf16x8 af[2], bfr[2];
#pragma unroll
      for (int m = 0; m < 2; ++m) {
        const int row = wr * 32 + m * 16 + lr;
        af[m] = ldbf8((const unsigned short*)((char*)&As[buf][0] + row * 128 +
                                              ((h2 * 64 + lg * 16) ^ swzc)));
      }
#pragma unroll
      for (int n = 0; n < 2; ++n) {
        const int row = wc * 32 + n * 16 + lr;
        bfr[n] = ldbf8((const unsigned short*)((char*)&Bs[buf][0] + row * 128 +
                                               ((h2 * 64 + lg * 16) ^ swzc)));
      }
#pragma unroll
      for (int m = 0; m < 2; ++m)
#pragma unroll
        for (int n = 0; n < 2; ++n) acc[m][n] = MFMA(af[m], bfr[n], acc[m][n]);
    }
    if (c < 15) writeB(buf ^ 1);
    __syncthreads();
  }

#pragma unroll
  for (int m = 0; m < 2; ++m) {
    const int mr = bm + wr * 32 + m * 16 + lg * 4;
#pragma unroll
    for (int nt = 0; nt < 2; ++nt) {
      const int n = bn + wc * 32 + nt * 16 + lr;
      const float bb = bias[n];
#pragma unroll
      for (int r = 0; r < 4; ++r) Out[(size_t)(mr + r) * N + n] = acc[m][nt][r] + bb;
    }
  }
}

// Flash attention v12: v11 with int8 Mf (cndmask C-init). WG-shared K/V glds
// staging (dbuf), fixed-offset softmax, cvt_pk P-pack, setprio, hoisted l.
__global__ __launch_bounds__(256)
void attn_v12(const unsigned short* __restrict__ Qb,
              const unsigned short* __restrict__ Kf,
              const unsigned short* __restrict__ Vf,
              const unsigned char* __restrict__ Mf8,
              unsigned short* __restrict__ ctx) {
  __shared__ __align__(16) unsigned short S[2][8192];
  __shared__ __align__(16) unsigned short sP[4][16 * 64];
  const int lid = blockIdx.x + (blockIdx.y << 6);
  const int xcd = lid & 7, slot = lid >> 3;
  const int bh = ((slot >> 4) << 3) + xcd;
  const int qb = slot & 15;
  const int b = bh >> 4, h = bh & 15;
  const int t = threadIdx.x, w = t >> 6, wl = t & 63, lr = wl & 15, lg = wl >> 4;
  const int q0 = qb * 64 + w * 16;
  const int swz = (lr & 7) << 4;

  const unsigned short* qp = Qb + (size_t)(b * 1024 + q0 + lr) * 1024 + h * 64 + lg * 8;
  const bf16x8 bq0 = ldbf8(qp);
  const bf16x8 bq1 = ldbf8(qp + 32);

  const unsigned short* KfB = Kf + (size_t)bh * 65536;
  const unsigned short* VfB = Vf + (size_t)bh * 65536;
  const unsigned char* mfp = Mf8 + (size_t)((b * 64 + qb * 4 + w) * 64) * 256 + wl * 4;

  f32x4 O[4];
  float l_ = 0.f;
#pragma unroll
  for (int dt = 0; dt < 4; ++dt) O[dt] = f32x4{0.f, 0.f, 0.f, 0.f};
  unsigned short* sp = &sP[w][0];

  auto stage = [&](int kc, int buf) {
    const unsigned short* srcs[4] = {KfB + kc * 2048, KfB + 32768 + kc * 2048,
                                     VfB + kc * 4096, VfB + kc * 4096 + 2048};
#pragma unroll
    for (int r = 0; r < 4; ++r) {
      const char* g = (const char*)(srcs[r] + (size_t)t * 8);
      char* l = (char*)&S[buf][r * 2048 + w * 512];
      glds16(g, l);
    }
  };

  stage(0, 0);
  __syncthreads();

  for (int kc = 0; kc < 16; ++kc) {
    const int buf = kc & 1;
    if (kc < 15) stage(kc + 1, buf ^ 1);

    uchar4 mk[4];
#pragma unroll
    for (int t4 = 0; t4 < 4; ++t4)
      mk[t4] = *reinterpret_cast<const uchar4*>(mfp + (size_t)(kc * 4 + t4) * 256);

    bf16x8 ak[4][2];
#pragma unroll
    for (int t4 = 0; t4 < 4; ++t4) {
      ak[t4][0] = ldbf8(&S[buf][t4 * 512 + wl * 8]);
      ak[t4][1] = ldbf8(&S[buf][2048 + t4 * 512 + wl * 8]);
    }

    f32x4 sc[4];
    __builtin_amdgcn_s_setprio(1);
#pragma unroll
    for (int t4 = 0; t4 < 4; ++t4) {
      f32x4 a;
      a[0] = mk[t4].x ? -1.4427e9f : -24.f;
      a[1] = mk[t4].y ? -1.4427e9f : -24.f;
      a[2] = mk[t4].z ? -1.4427e9f : -24.f;
      a[3] = mk[t4].w ? -1.4427e9f : -24.f;
      a = MFMA(ak[t4][0], bq0, a);
      a = MFMA(ak[t4][1], bq1, a);
      sc[t4] = a;
    }
    __builtin_amdgcn_s_setprio(0);

#pragma unroll
    for (int t4 = 0; t4 < 4; ++t4) {
      const float e0 = EXP2(sc[t4][0]), e1 = EXP2(sc[t4][1]);
      const float e2 = EXP2(sc[t4][2]), e3 = EXP2(sc[t4][3]);
      l_ += (e0 + e1) + (e2 + e3);
      uint2 pw;
      pw.x = cvtpk(e0, e1);
      pw.y = cvtpk(e2, e3);
      *reinterpret_cast<uint2*>((char*)sp + lr * 128 + ((t4 * 32 + lg * 8) ^ swz)) = pw;
    }

    __builtin_amdgcn_s_setprio(1);
#pragma unroll
    for (int ks = 0; ks < 2; ++ks) {
      bf16x8 ap =
          ldbf8((const unsigned short*)((char*)sp + lr * 128 + ((ks * 64 + lg * 16) ^ swz)));
#pragma unroll
      for (int dt = 0; dt < 4; ++dt) {
        bf16x8 bv = ldbf8(&S[buf][4096 + ks * 2048 + dt * 512 + wl * 8]);
        O[dt] = MFMA(ap, bv, O[dt]);
      }
    }
    __builtin_amdgcn_s_setprio(0);

    __syncthreads();
  }

  l_ += __shfl_xor(l_, 16);
  l_ += __shfl_xor(l_, 32);

  float linv[4];
#pragma unroll
  for (int r = 0; r < 4; ++r) linv[r] = 1.0f / __shfl(l_, lg * 4 + r);
#pragma unroll
  for (int dt = 0; dt < 4; ++dt)
#pragma unroll
    for (int r = 0; r < 4; ++r)
      ctx[(size_t)(b * 1024 + q0 + lg * 4 + r) * 1024 + h * 64 + dt * 16 + lr] =
          f2b(O[dt][r] * linv[r]);
}

extern "C" void kernel_launch(void* const* d_in, const int* in_sizes, int n_in,
                              void* d_out, int out_size, void* d_ws, size_t ws_size,
                              hipStream_t stream) {
  const float* query = (const float*)d_in[0];
  const float* key   = (const float*)d_in[1];
  const float* value = (const float*)d_in[2];
  const int*   mask  = (const int*)d_in[3];
  const float* wq = (const float*)d_in[4];
  const float* bq = (const float*)d_in[5];
  const float* wk = (const float*)d_in[6];
  const float* bk = (const float*)d_in[7];
  const float* wv = (const float*)d_in[8];
  const float* bv = (const float*)d_in[9];
  const float* wo = (const float*)d_in[10];
  const float* bo = (const float*)d_in[11];
  float* out = (float*)d_out;

  // ws [0..32MB): Qb, Kf, Vf, ctx (bf16, 8MB each). ctx slot doubles as Abfk
  // during the projection. d_out: Abfq [0..8M) then Mf8 overlays it (4MB);
  // Wb [8..14M). Abfv at ws+32MB only if ws_size >= 40MB. gemm_out reads wo
  // (f32) directly.
  const size_t SZ = (size_t)4096 * 1024;
  unsigned short* Qb   = (unsigned short*)d_ws;
  unsigned short* Kf   = Qb + SZ;
  unsigned short* Vf   = Kf + SZ;
  unsigned short* ctx  = Vf + SZ;
  unsigned short* Abfq = (unsigned short*)d_out;
  unsigned short* Wb   = Abfq + SZ;
  unsigned char*  Mf8  = (unsigned char*)d_out;   // after projection
  unsigned short* Abfk = ctx;                     // before attn
  const bool big = ws_size >= (size_t)40 * 1024 * 1024;
  unsigned short* Abfv = big ? (ctx + SZ) : nullptr;  // ws+32MB

  const float qscale = 0.125f * 1.4426950408889634f;  // 1/sqrt(64) * log2(e)
  dim3 blk(256);
  prep<<<big ? 7680 : 5632, blk, 0, stream>>>(query, key, value, wq, wk, wv,
                                              Abfq, Abfk, Abfv, Wb);
  gemm_proj<<<dim3(32, 8, 3), dim3(512), 0, stream>>>(Abfq, Abfk, Abfv, value, Wb,
                                                      bq, bk, bv, Qb, Kf, Vf, qscale);
  maskcvt<<<4096, blk, 0, stream>>>(mask, Mf8);
  attn_v12<<<dim3(64, 16), blk, 0, stream>>>(Qb, Kf, Vf, Mf8, ctx);
  gemm_out<<<dim3(32, 16), dim3(512), 0, stream>>>(ctx, wo, bo, out);
}

// Round 24
// 111.166 us; speedup vs baseline: 1.0427x; 1.0115x over previous
//
#include <hip/hip_runtime.h>
#include <hip/hip_bf16.h>

// MHA forward: B=4, S=1024, D=1024, H=16, DK=64.
// v24: R23 base + bit-packed mask (Mfb, 512KB; 1 u16 load/lane/chunk) and
// maskcvt FUSED into prep (Mfb coexists with Abfq/Wb in d_out — no aliasing).
// gemm_proj (counted-vmcnt), gemm_out, attn structure unchanged.

typedef __bf16 bf16x8 __attribute__((ext_vector_type(8)));
typedef float f32x4 __attribute__((ext_vector_type(4)));
typedef unsigned short us8 __attribute__((ext_vector_type(8)));
typedef unsigned short us4 __attribute__((ext_vector_type(4)));

#define MFMA(a, b, c) __builtin_amdgcn_mfma_f32_16x16x32_bf16(a, b, c, 0, 0, 0)
#define EXP2(x) __builtin_amdgcn_exp2f(x)

__device__ __forceinline__ unsigned short f2b(float f) {
  return __builtin_bit_cast(unsigned short, __float2bfloat16(f));
}
__device__ __forceinline__ unsigned cvtpk(float lo, float hi) {
  unsigned r;
  asm("v_cvt_pk_bf16_f32 %0, %1, %2" : "=v"(r) : "v"(lo), "v"(hi));
  return r;
}
__device__ __forceinline__ bf16x8 ldbf8(const unsigned short* p) {
  return __builtin_bit_cast(bf16x8, *reinterpret_cast<const us8*>(p));
}
__device__ __forceinline__ us8 cvt8(float4 a, float4 b) {
  us8 o;
  o[0] = f2b(a.x); o[1] = f2b(a.y); o[2] = f2b(a.z); o[3] = f2b(a.w);
  o[4] = f2b(b.x); o[5] = f2b(b.y); o[6] = f2b(b.z); o[7] = f2b(b.w);
  return o;
}
__device__ __forceinline__ void glds16(const void* g, void* l) {
  __builtin_amdgcn_global_load_lds(
      (const __attribute__((address_space(1))) unsigned int*)g,
      (__attribute__((address_space(3))) unsigned int*)l, 16, 0, 0);
}

// prep (fused): bid [0,1536): wq/wk/wv f32->bf16 -> Wb.
//   [1536,3584): query -> Abfq; [3584,5632): key -> Abfk;
//   [5632,nconv): value -> Abfv (only when ws big).
//   [nconv, nconv+1024): mask bit-pack -> Mfb. Tile mt=(b,qt,kc); lane wl
//   packs 16 bits (t4*4+r) = mask[b][qt*16+lr][kc*64+t4*16+lg*4+r] != 0.
__global__ __launch_bounds__(256)
void prep(const float* __restrict__ query, const float* __restrict__ key,
          const float* __restrict__ value, const float* __restrict__ wq,
          const float* __restrict__ wk, const float* __restrict__ wv,
          const int* __restrict__ mask,
          unsigned short* __restrict__ Abfq, unsigned short* __restrict__ Abfk,
          unsigned short* __restrict__ Abfv, unsigned short* __restrict__ Wb,
          unsigned short* __restrict__ Mfb, int nconv) {
  const int bid = blockIdx.x, tid = threadIdx.x;
  if (bid >= nconv) {
    const int mt = (bid - nconv) * 4 + (tid >> 6);  // 0..4095 = (b,qt,kc)
    const int wl = tid & 63, lr = wl & 15, lg = wl >> 4;
    const int kc = mt & 15, qt = (mt >> 4) & 63, b = mt >> 10;
    const int* mrow = mask + (size_t)(b * 1024 + qt * 16 + lr) * 1024 + kc * 64 + lg * 4;
    unsigned bits = 0;
#pragma unroll
    for (int t4 = 0; t4 < 4; ++t4) {
      const int4 mv = *reinterpret_cast<const int4*>(mrow + t4 * 16);
      bits |= (mv.x != 0 ? 1u : 0u) << (t4 * 4 + 0);
      bits |= (mv.y != 0 ? 1u : 0u) << (t4 * 4 + 1);
      bits |= (mv.z != 0 ? 1u : 0u) << (t4 * 4 + 2);
      bits |= (mv.w != 0 ? 1u : 0u) << (t4 * 4 + 3);
    }
    Mfb[(size_t)mt * 64 + wl] = (unsigned short)bits;
    return;
  }
  const float* src;
  unsigned short* dst;
  size_t off;
  if (bid < 1536) {
    const int widx = bid >> 9;
    src = (widx == 0) ? wq : (widx == 1) ? wk : wv;
    dst = Wb + (size_t)widx * 1048576;
    off = (size_t)(bid & 511) * 2048 + tid * 8;
  } else if (bid < 3584) {
    src = query; dst = Abfq; off = (size_t)(bid - 1536) * 2048 + tid * 8;
  } else if (bid < 5632) {
    src = key; dst = Abfk; off = (size_t)(bid - 3584) * 2048 + tid * 8;
  } else {
    src = value; dst = Abfv; off = (size_t)(bid - 5632) * 2048 + tid * 8;
  }
  const float4* p = reinterpret_cast<const float4*>(src + off);
  *reinterpret_cast<us8*>(dst + off) = cvt8(p[0], p[1]);
}

// Projection GEMM v22 (unchanged): BM=128, BN=128, BK=32; 512 threads; 3-buf
// counted-vmcnt pipeline; conflict-free row-pair-interleaved LDS layout.
__global__ __launch_bounds__(512, 6)
void gemm_proj(const unsigned short* __restrict__ Aq,
               const unsigned short* __restrict__ Ak,
               const unsigned short* __restrict__ Av_bf,
               const float* __restrict__ Av_f32,
               const unsigned short* __restrict__ Wb,
               const float* __restrict__ bq, const float* __restrict__ bk,
               const float* __restrict__ bv, unsigned short* __restrict__ Qb,
               unsigned short* __restrict__ Kf, unsigned short* __restrict__ Vf,
               float qscale) {
  constexpr int K = 1024, N = 1024;
  __shared__ __align__(16) unsigned short As[3][128 * 32];
  __shared__ __align__(16) unsigned short Bs[3][128 * 32];
  const int lid = blockIdx.x + (blockIdx.y << 5) + (blockIdx.z << 8);
  const int xcd = lid & 7, slot = lid >> 3;
  const int chunk = ((slot >> 3) << 3) + xcd;
  const int z = chunk >> 5;
  const int bm = (chunk & 31) * 128;
  const int bn = (slot & 7) * 128;

  const unsigned short* Abf = (z == 0) ? Aq : (z == 1) ? Ak : Av_bf;
  const bool f32path = (z == 2) && (Av_bf == nullptr);
  const unsigned short* Bw = Wb + (size_t)z * 1048576;
  const float* bias = (z == 0) ? bq : (z == 1) ? bk : bv;
  const int t = threadIdx.x;
  const int w = t >> 6, lane = t & 63, lr = lane & 15, lg = lane >> 4;
  const int wr = w >> 2, wc = w & 3;

  const int sline = t >> 3;
  const int su = (t & 7) ^ (sline & 7);
  const int srow = sline * 2 + (su >> 2);
  const int scol = (su & 3) * 8;

  f32x4 acc[4][2];
#pragma unroll
  for (int m = 0; m < 4; ++m)
#pragma unroll
    for (int n = 0; n < 2; ++n) acc[m][n] = f32x4{0.f, 0.f, 0.f, 0.f};

  auto stageA = [&](int k0, int buf) {
    const char* g = (const char*)(Abf + (size_t)(bm + srow) * 1024 + k0 + scol);
    char* l = (char*)&As[buf][0] + (w * 64) * 16;
    glds16(g, l);
  };
  auto stageB = [&](int k0, int buf) {
    const char* g = (const char*)(Bw + (size_t)(bn + srow) * 1024 + k0 + scol);
    char* l = (char*)&Bs[buf][0] + (w * 64) * 16;
    glds16(g, l);
  };
#define STA8(buf, v)                                                           \
  { *reinterpret_cast<us8*>((char*)&As[buf][0] + t * 16) = (v); }
#define RDOFF(row) (((row) >> 1) * 128 +                                       \
                    (((lg | (((row) & 1) << 2)) ^ (((row) >> 1) & 7)) * 16))
#define COMPUTE(buf)                                                           \
  {                                                                            \
    bf16x8 af[4], bfr[2];                                                      \
    _Pragma("unroll") for (int m = 0; m < 4; ++m) {                            \
      const int row = wr * 64 + m * 16 + lr;                                   \
      af[m] = ldbf8((const unsigned short*)((char*)&As[buf][0] + RDOFF(row))); \
    }                                                                          \
    _Pragma("unroll") for (int n = 0; n < 2; ++n) {                            \
      const int row = wc * 32 + n * 16 + lr;                                   \
      bfr[n] = ldbf8((const unsigned short*)((char*)&Bs[buf][0] + RDOFF(row)));\
    }                                                                          \
    _Pragma("unroll") for (int m = 0; m < 4; ++m)                              \
        _Pragma("unroll") for (int n = 0; n < 2; ++n)                          \
        acc[m][n] = MFMA(af[m], bfr[n], acc[m][n]);                            \
  }

  if (!f32path) {
    stageA(0, 0);
    stageB(0, 0);
    stageA(32, 1);
    stageB(32, 1);
    for (int c = 0; c < 32; ++c) {
      const int buf = c % 3;
      if (c < 31) {
        asm volatile("s_waitcnt vmcnt(2)" ::: "memory");
      } else {
        asm volatile("s_waitcnt vmcnt(0)" ::: "memory");
      }
      __builtin_amdgcn_s_barrier();
      if (c < 30) {
        const int nb = (c + 2) % 3;
        stageA((c + 2) * 32, nb);
        stageB((c + 2) * 32, nb);
      }
      COMPUTE(buf)
    }
  } else {
    {
      const float4* p =
          reinterpret_cast<const float4*>(Av_f32 + (size_t)(bm + srow) * K + scol);
      STA8(0, cvt8(p[0], p[1]));
      stageB(0, 0);
    }
    __syncthreads();
    for (int c = 0; c < 32; ++c) {
      const int buf = c & 1;
      float4 fa[2];
      if (c < 31) {
        const int k1 = (c + 1) * 32;
        const float4* p = reinterpret_cast<const float4*>(
            Av_f32 + (size_t)(bm + srow) * K + k1 + scol);
        fa[0] = p[0];
        fa[1] = p[1];
        stageB(k1, buf ^ 1);
      }
      COMPUTE(buf)
      if (c < 31) {
        STA8(buf ^ 1, cvt8(fa[0], fa[1]));
      }
      __syncthreads();
    }
  }
#undef STA8
#undef RDOFF
#undef COMPUTE

#pragma unroll
  for (int m = 0; m < 4; ++m) {
    const int mr = bm + wr * 64 + m * 16 + lg * 4;
#pragma unroll
    for (int nt = 0; nt < 2; ++nt) {
      const int n = bn + wc * 32 + nt * 16 + lr;
      const float bb = bias[n];
      if (z == 0) {
#pragma unroll
        for (int r = 0; r < 4; ++r)
          Qb[(size_t)(mr + r) * N + n] = f2b((acc[m][nt][r] + bb) * qscale);
      } else if (z == 1) {
        // Kf: K[bh][s][d] -> bh*65536 + (d>>5)*32768 + (s>>4)*512
        //     + ((s&15)|(((d>>3)&3)<<4))*8 + (d&7)
        const int b2 = mr >> 10, s0 = mr & 1023, hh = n >> 6, dd = n & 63;
        const size_t base = (size_t)(b2 * 16 + hh) * 65536 + (size_t)(dd >> 5) * 32768 +
                            (size_t)(s0 >> 4) * 512 +
                            (size_t)((s0 & 15) | (((dd >> 3) & 3) << 4)) * 8 + (dd & 7);
#pragma unroll
        for (int r = 0; r < 4; ++r) Kf[base + r * 8] = f2b(acc[m][nt][r] + bb);
      } else {
        // Vf: V[bh][s][d] -> bh*65536 + (s>>5)*2048 + (d>>4)*512
        //     + ((d&15)|(((s>>3)&3)<<4))*8 + (s&7)
        const int b2 = mr >> 10, s0 = mr & 1023, hh = n >> 6, dd = n & 63;
        const size_t base = (size_t)(b2 * 16 + hh) * 65536 + (size_t)(s0 >> 5) * 2048 +
                            (size_t)(dd >> 4) * 512 +
                            (size_t)((dd & 15) | (((s0 >> 3) & 3) << 4)) * 8 + (s0 & 7);
        us4 pk;
#pragma unroll
        for (int r = 0; r < 4; ++r) pk[r] = f2b(acc[m][nt][r] + bb);
        *reinterpret_cast<us4*>(&Vf[base]) = pk;
      }
    }
  }
}

// Output projection v21 (unchanged): BM=128, BN=64, BK=64; 512 threads; A via
// glds, B staged directly from f32 wo (reg convert, T14 split).
__global__ __launch_bounds__(512, 4)
void gemm_out(const unsigned short* __restrict__ A, const float* __restrict__ Bwf,
              const float* __restrict__ bias, float* __restrict__ Out) {
  constexpr int K = 1024, N = 1024;
  __shared__ __align__(16) unsigned short As[2][128 * 64];
  __shared__ __align__(16) unsigned short Bs[2][64 * 64];
  const int lid = blockIdx.x + (blockIdx.y << 5);
  const int xcd = lid & 7, slot = lid >> 3;
  const int chunk = ((slot >> 5) << 3) + xcd;
  const int pos = slot & 31;
  const int bm = ((chunk << 1) + (pos >> 4)) * 128;
  const int bn = (pos & 15) * 64;
  const int t = threadIdx.x;
  const int w = t >> 6, lane = t & 63, lr = lane & 15, lg = lane >> 4;
  const int wr = w >> 1, wc = w & 1;
  const int swzc = (lr & 7) << 4;
  const int brow = t >> 3, bcol = (t & 7) * 8, bcb = (t & 7) * 16;

  f32x4 acc[2][2];
#pragma unroll
  for (int m = 0; m < 2; ++m)
#pragma unroll
    for (int n = 0; n < 2; ++n) acc[m][n] = f32x4{0.f, 0.f, 0.f, 0.f};

  auto stageA = [&](int k0, int buf) {
#pragma unroll
    for (int it = 0; it < 2; ++it) {
      const int s = it * 512 + t, row = s >> 3, cb = (s & 7) * 16;
      const char* g = (const char*)A + ((size_t)(bm + row) * 1024 + k0) * 2 +
                      (cb ^ ((row & 7) << 4));
      char* l = (char*)&As[buf][0] + (it * 512 + w * 64) * 16;
      glds16(g, l);
    }
  };
  float4 fb[2];
  auto loadB = [&](int k0) {
    const float4* p =
        reinterpret_cast<const float4*>(Bwf + (size_t)(bn + brow) * 1024 + k0 + bcol);
    fb[0] = p[0];
    fb[1] = p[1];
  };
  auto writeB = [&](int buf) {
    *reinterpret_cast<us8*>((char*)&Bs[buf][0] + brow * 128 +
                            (bcb ^ ((brow & 7) << 4))) = cvt8(fb[0], fb[1]);
  };

  stageA(0, 0);
  loadB(0);
  writeB(0);
  __syncthreads();

  for (int c = 0; c < 16; ++c) {
    const int buf = c & 1;
    if (c < 15) {
      const int k1 = (c + 1) * 64;
      stageA(k1, buf ^ 1);
      loadB(k1);
    }
#pragma unroll
    for (int h2 = 0; h2 < 2; ++h2) {
      bf16x8 af[2], bfr[2];
#pragma unroll
      for (int m = 0; m < 2; ++m) {
        const int row = wr * 32 + m * 16 + lr;
        af[m] = ldbf8((const unsigned short*)((char*)&As[buf][0] + row * 128 +
                                              ((h2 * 64 + lg * 16) ^ swzc)));
      }
#pragma unroll
      for (int n = 0; n < 2; ++n) {
        const int row = wc * 32 + n * 16 + lr;
        bfr[n] = ldbf8((const unsigned short*)((char*)&Bs[buf][0] + row * 128 +
                                               ((h2 * 64 + lg * 16) ^ swzc)));
      }
#pragma unroll
      for (int m = 0; m < 2; ++m)
#pragma unroll
        for (int n = 0; n < 2; ++n) acc[m][n] = MFMA(af[m], bfr[n], acc[m][n]);
    }
    if (c < 15) writeB(buf ^ 1);
    __syncthreads();
  }

#pragma unroll
  for (int m = 0; m < 2; ++m) {
    const int mr = bm + wr * 32 + m * 16 + lg * 4;
#pragma unroll
    for (int nt = 0; nt < 2; ++nt) {
      const int n = bn + wc * 32 + nt * 16 + lr;
      const float bb = bias[n];
#pragma unroll
      for (int r = 0; r < 4; ++r) Out[(size_t)(mr + r) * N + n] = acc[m][nt][r] + bb;
    }
  }
}

// Flash attention v13: v12 with bit-packed mask (1 u16 load/lane/chunk).
// WG-shared K/V glds staging (dbuf), fixed-offset softmax, cvt_pk, setprio.
__global__ __launch_bounds__(256)
void attn_v13(const unsigned short* __restrict__ Qb,
              const unsigned short* __restrict__ Kf,
              const unsigned short* __restrict__ Vf,
              const unsigned short* __restrict__ Mfb,
              unsigned short* __restrict__ ctx) {
  __shared__ __align__(16) unsigned short S[2][8192];
  __shared__ __align__(16) unsigned short sP[4][16 * 64];
  const int lid = blockIdx.x + (blockIdx.y << 6);
  const int xcd = lid & 7, slot = lid >> 3;
  const int bh = ((slot >> 4) << 3) + xcd;
  const int qb = slot & 15;
  const int b = bh >> 4, h = bh & 15;
  const int t = threadIdx.x, w = t >> 6, wl = t & 63, lr = wl & 15, lg = wl >> 4;
  const int q0 = qb * 64 + w * 16;
  const int swz = (lr & 7) << 4;

  const unsigned short* qp = Qb + (size_t)(b * 1024 + q0 + lr) * 1024 + h * 64 + lg * 8;
  const bf16x8 bq0 = ldbf8(qp);
  const bf16x8 bq1 = ldbf8(qp + 32);

  const unsigned short* KfB = Kf + (size_t)bh * 65536;
  const unsigned short* VfB = Vf + (size_t)bh * 65536;
  // Mfb tile mt = (b*64 + qt)*16 + kc, qt = qb*4 + w; addr = mt*64 + wl.
  const unsigned short* mfp = Mfb + (size_t)((b * 64 + qb * 4 + w) * 16) * 64 + wl;

  f32x4 O[4];
  float l_ = 0.f;
#pragma unroll
  for (int dt = 0; dt < 4; ++dt) O[dt] = f32x4{0.f, 0.f, 0.f, 0.f};
  unsigned short* sp = &sP[w][0];

  auto stage = [&](int kc, int buf) {
    const unsigned short* srcs[4] = {KfB + kc * 2048, KfB + 32768 + kc * 2048,
                                     VfB + kc * 4096, VfB + kc * 4096 + 2048};
#pragma unroll
    for (int r = 0; r < 4; ++r) {
      const char* g = (const char*)(srcs[r] + (size_t)t * 8);
      char* l = (char*)&S[buf][r * 2048 + w * 512];
      glds16(g, l);
    }
  };

  stage(0, 0);
  __syncthreads();

  for (int kc = 0; kc < 16; ++kc) {
    const int buf = kc & 1;
    if (kc < 15) stage(kc + 1, buf ^ 1);

    const unsigned bits = mfp[kc * 64];

    bf16x8 ak[4][2];
#pragma unroll
    for (int t4 = 0; t4 < 4; ++t4) {
      ak[t4][0] = ldbf8(&S[buf][t4 * 512 + wl * 8]);
      ak[t4][1] = ldbf8(&S[buf][2048 + t4 * 512 + wl * 8]);
    }

    f32x4 sc[4];
    __builtin_amdgcn_s_setprio(1);
#pragma unroll
    for (int t4 = 0; t4 < 4; ++t4) {
      f32x4 a;
#pragma unroll
      for (int r = 0; r < 4; ++r)
        a[r] = (bits >> (t4 * 4 + r)) & 1u ? -1.4427e9f : -24.f;
      a = MFMA(ak[t4][0], bq0, a);
      a = MFMA(ak[t4][1], bq1, a);
      sc[t4] = a;
    }
    __builtin_amdgcn_s_setprio(0);

#pragma unroll
    for (int t4 = 0; t4 < 4; ++t4) {
      const float e0 = EXP2(sc[t4][0]), e1 = EXP2(sc[t4][1]);
      const float e2 = EXP2(sc[t4][2]), e3 = EXP2(sc[t4][3]);
      l_ += (e0 + e1) + (e2 + e3);
      uint2 pw;
      pw.x = cvtpk(e0, e1);
      pw.y = cvtpk(e2, e3);
      *reinterpret_cast<uint2*>((char*)sp + lr * 128 + ((t4 * 32 + lg * 8) ^ swz)) = pw;
    }

    __builtin_amdgcn_s_setprio(1);
#pragma unroll
    for (int ks = 0; ks < 2; ++ks) {
      bf16x8 ap =
          ldbf8((const unsigned short*)((char*)sp + lr * 128 + ((ks * 64 + lg * 16) ^ swz)));
#pragma unroll
      for (int dt = 0; dt < 4; ++dt) {
        bf16x8 bv = ldbf8(&S[buf][4096 + ks * 2048 + dt * 512 + wl * 8]);
        O[dt] = MFMA(ap, bv, O[dt]);
      }
    }
    __builtin_amdgcn_s_setprio(0);

    __syncthreads();
  }

  l_ += __shfl_xor(l_, 16);
  l_ += __shfl_xor(l_, 32);

  float linv[4];
#pragma unroll
  for (int r = 0; r < 4; ++r) linv[r] = 1.0f / __shfl(l_, lg * 4 + r);
#pragma unroll
  for (int dt = 0; dt < 4; ++dt)
#pragma unroll
    for (int r = 0; r < 4; ++r)
      ctx[(size_t)(b * 1024 + q0 + lg * 4 + r) * 1024 + h * 64 + dt * 16 + lr] =
          f2b(O[dt][r] * linv[r]);
}

extern "C" void kernel_launch(void* const* d_in, const int* in_sizes, int n_in,
                              void* d_out, int out_size, void* d_ws, size_t ws_size,
                              hipStream_t stream) {
  const float* query = (const float*)d_in[0];
  const float* key   = (const float*)d_in[1];
  const float* value = (const float*)d_in[2];
  const int*   mask  = (const int*)d_in[3];
  const float* wq = (const float*)d_in[4];
  const float* bq = (const float*)d_in[5];
  const float* wk = (const float*)d_in[6];
  const float* bk = (const float*)d_in[7];
  const float* wv = (const float*)d_in[8];
  const float* bv = (const float*)d_in[9];
  const float* wo = (const float*)d_in[10];
  const float* bo = (const float*)d_in[11];
  float* out = (float*)d_out;

  // ws [0..32MB): Qb, Kf, Vf, ctx (bf16, 8MB each). ctx slot doubles as Abfk
  // during the projection. d_out: Abfq [0,8MB) + Wb [8,14MB) + Mfb [14,14.5MB)
  // — all coexist (no aliasing), dead before gemm_out overwrites d_out.
  // Abfv at ws+32MB only if ws_size >= 40MB. gemm_out reads wo (f32) directly.
  const size_t SZ = (size_t)4096 * 1024;
  unsigned short* Qb   = (unsigned short*)d_ws;
  unsigned short* Kf   = Qb + SZ;
  unsigned short* Vf   = Kf + SZ;
  unsigned short* ctx  = Vf + SZ;
  unsigned short* Abfq = (unsigned short*)d_out;
  unsigned short* Wb   = Abfq + SZ;
  unsigned short* Mfb  = (unsigned short*)((char*)d_out + (size_t)14 * 1024 * 1024);
  unsigned short* Abfk = ctx;                     // before attn
  const bool big = ws_size >= (size_t)40 * 1024 * 1024;
  unsigned short* Abfv = big ? (ctx + SZ) : nullptr;  // ws+32MB
  const int nconv = big ? 7680 : 5632;

  const float qscale = 0.125f * 1.4426950408889634f;  // 1/sqrt(64) * log2(e)
  dim3 blk(256);
  prep<<<nconv + 1024, blk, 0, stream>>>(query, key, value, wq, wk, wv, mask,
                                         Abfq, Abfk, Abfv, Wb, Mfb, nconv);
  gemm_proj<<<dim3(32, 8, 3), dim3(512), 0, stream>>>(Abfq, Abfk, Abfv, value, Wb,
                                                      bq, bk, bv, Qb, Kf, Vf, qscale);
  attn_v13<<<dim3(64, 16), blk, 0, stream>>>(Qb, Kf, Vf, Mfb, ctx);
  gemm_out<<<dim3(32, 16), dim3(512), 0, stream>>>(ctx, wo, bo, out);
}

// Round 25
// 105.109 us; speedup vs baseline: 1.1028x; 1.0576x over previous
//
#include <hip/hip_runtime.h>
#include <hip/hip_bf16.h>

// MHA forward: B=4, S=1024, D=1024, H=16, DK=64.
// v25: R24 base + attn_v14: 512-thread WGs (8 waves = 8 q-tiles of one bh)
// share ONE K/V staging pass per chunk — halves staging glds + K/V L2 reads
// at identical waves/CU. Everything else = R24 (best 111.2us).

typedef __bf16 bf16x8 __attribute__((ext_vector_type(8)));
typedef float f32x4 __attribute__((ext_vector_type(4)));
typedef unsigned short us8 __attribute__((ext_vector_type(8)));
typedef unsigned short us4 __attribute__((ext_vector_type(4)));

#define MFMA(a, b, c) __builtin_amdgcn_mfma_f32_16x16x32_bf16(a, b, c, 0, 0, 0)
#define EXP2(x) __builtin_amdgcn_exp2f(x)

__device__ __forceinline__ unsigned short f2b(float f) {
  return __builtin_bit_cast(unsigned short, __float2bfloat16(f));
}
__device__ __forceinline__ unsigned cvtpk(float lo, float hi) {
  unsigned r;
  asm("v_cvt_pk_bf16_f32 %0, %1, %2" : "=v"(r) : "v"(lo), "v"(hi));
  return r;
}
__device__ __forceinline__ bf16x8 ldbf8(const unsigned short* p) {
  return __builtin_bit_cast(bf16x8, *reinterpret_cast<const us8*>(p));
}
__device__ __forceinline__ us8 cvt8(float4 a, float4 b) {
  us8 o;
  o[0] = f2b(a.x); o[1] = f2b(a.y); o[2] = f2b(a.z); o[3] = f2b(a.w);
  o[4] = f2b(b.x); o[5] = f2b(b.y); o[6] = f2b(b.z); o[7] = f2b(b.w);
  return o;
}
__device__ __forceinline__ void glds16(const void* g, void* l) {
  __builtin_amdgcn_global_load_lds(
      (const __attribute__((address_space(1))) unsigned int*)g,
      (__attribute__((address_space(3))) unsigned int*)l, 16, 0, 0);
}

// prep (fused): bid [0,1536): wq/wk/wv f32->bf16 -> Wb.
//   [1536,3584): query -> Abfq; [3584,5632): key -> Abfk;
//   [5632,nconv): value -> Abfv (only when ws big).
//   [nconv, nconv+1024): mask bit-pack -> Mfb.
__global__ __launch_bounds__(256)
void prep(const float* __restrict__ query, const float* __restrict__ key,
          const float* __restrict__ value, const float* __restrict__ wq,
          const float* __restrict__ wk, const float* __restrict__ wv,
          const int* __restrict__ mask,
          unsigned short* __restrict__ Abfq, unsigned short* __restrict__ Abfk,
          unsigned short* __restrict__ Abfv, unsigned short* __restrict__ Wb,
          unsigned short* __restrict__ Mfb, int nconv) {
  const int bid = blockIdx.x, tid = threadIdx.x;
  if (bid >= nconv) {
    const int mt = (bid - nconv) * 4 + (tid >> 6);
    const int wl = tid & 63, lr = wl & 15, lg = wl >> 4;
    const int kc = mt & 15, qt = (mt >> 4) & 63, b = mt >> 10;
    const int* mrow = mask + (size_t)(b * 1024 + qt * 16 + lr) * 1024 + kc * 64 + lg * 4;
    unsigned bits = 0;
#pragma unroll
    for (int t4 = 0; t4 < 4; ++t4) {
      const int4 mv = *reinterpret_cast<const int4*>(mrow + t4 * 16);
      bits |= (mv.x != 0 ? 1u : 0u) << (t4 * 4 + 0);
      bits |= (mv.y != 0 ? 1u : 0u) << (t4 * 4 + 1);
      bits |= (mv.z != 0 ? 1u : 0u) << (t4 * 4 + 2);
      bits |= (mv.w != 0 ? 1u : 0u) << (t4 * 4 + 3);
    }
    Mfb[(size_t)mt * 64 + wl] = (unsigned short)bits;
    return;
  }
  const float* src;
  unsigned short* dst;
  size_t off;
  if (bid < 1536) {
    const int widx = bid >> 9;
    src = (widx == 0) ? wq : (widx == 1) ? wk : wv;
    dst = Wb + (size_t)widx * 1048576;
    off = (size_t)(bid & 511) * 2048 + tid * 8;
  } else if (bid < 3584) {
    src = query; dst = Abfq; off = (size_t)(bid - 1536) * 2048 + tid * 8;
  } else if (bid < 5632) {
    src = key; dst = Abfk; off = (size_t)(bid - 3584) * 2048 + tid * 8;
  } else {
    src = value; dst = Abfv; off = (size_t)(bid - 5632) * 2048 + tid * 8;
  }
  const float4* p = reinterpret_cast<const float4*>(src + off);
  *reinterpret_cast<us8*>(dst + off) = cvt8(p[0], p[1]);
}

// Projection GEMM v22 (unchanged): BM=128, BN=128, BK=32; 512 threads; 3-buf
// counted-vmcnt pipeline; conflict-free row-pair-interleaved LDS layout.
__global__ __launch_bounds__(512, 6)
void gemm_proj(const unsigned short* __restrict__ Aq,
               const unsigned short* __restrict__ Ak,
               const unsigned short* __restrict__ Av_bf,
               const float* __restrict__ Av_f32,
               const unsigned short* __restrict__ Wb,
               const float* __restrict__ bq, const float* __restrict__ bk,
               const float* __restrict__ bv, unsigned short* __restrict__ Qb,
               unsigned short* __restrict__ Kf, unsigned short* __restrict__ Vf,
               float qscale) {
  constexpr int K = 1024, N = 1024;
  __shared__ __align__(16) unsigned short As[3][128 * 32];
  __shared__ __align__(16) unsigned short Bs[3][128 * 32];
  const int lid = blockIdx.x + (blockIdx.y << 5) + (blockIdx.z << 8);
  const int xcd = lid & 7, slot = lid >> 3;
  const int chunk = ((slot >> 3) << 3) + xcd;
  const int z = chunk >> 5;
  const int bm = (chunk & 31) * 128;
  const int bn = (slot & 7) * 128;

  const unsigned short* Abf = (z == 0) ? Aq : (z == 1) ? Ak : Av_bf;
  const bool f32path = (z == 2) && (Av_bf == nullptr);
  const unsigned short* Bw = Wb + (size_t)z * 1048576;
  const float* bias = (z == 0) ? bq : (z == 1) ? bk : bv;
  const int t = threadIdx.x;
  const int w = t >> 6, lane = t & 63, lr = lane & 15, lg = lane >> 4;
  const int wr = w >> 2, wc = w & 3;

  const int sline = t >> 3;
  const int su = (t & 7) ^ (sline & 7);
  const int srow = sline * 2 + (su >> 2);
  const int scol = (su & 3) * 8;

  f32x4 acc[4][2];
#pragma unroll
  for (int m = 0; m < 4; ++m)
#pragma unroll
    for (int n = 0; n < 2; ++n) acc[m][n] = f32x4{0.f, 0.f, 0.f, 0.f};

  auto stageA = [&](int k0, int buf) {
    const char* g = (const char*)(Abf + (size_t)(bm + srow) * 1024 + k0 + scol);
    char* l = (char*)&As[buf][0] + (w * 64) * 16;
    glds16(g, l);
  };
  auto stageB = [&](int k0, int buf) {
    const char* g = (const char*)(Bw + (size_t)(bn + srow) * 1024 + k0 + scol);
    char* l = (char*)&Bs[buf][0] + (w * 64) * 16;
    glds16(g, l);
  };
#define STA8(buf, v)                                                           \
  { *reinterpret_cast<us8*>((char*)&As[buf][0] + t * 16) = (v); }
#define RDOFF(row) (((row) >> 1) * 128 +                                       \
                    (((lg | (((row) & 1) << 2)) ^ (((row) >> 1) & 7)) * 16))
#define COMPUTE(buf)                                                           \
  {                                                                            \
    bf16x8 af[4], bfr[2];                                                      \
    _Pragma("unroll") for (int m = 0; m < 4; ++m) {                            \
      const int row = wr * 64 + m * 16 + lr;                                   \
      af[m] = ldbf8((const unsigned short*)((char*)&As[buf][0] + RDOFF(row))); \
    }                                                                          \
    _Pragma("unroll") for (int n = 0; n < 2; ++n) {                            \
      const int row = wc * 32 + n * 16 + lr;                                   \
      bfr[n] = ldbf8((const unsigned short*)((char*)&Bs[buf][0] + RDOFF(row)));\
    }                                                                          \
    _Pragma("unroll") for (int m = 0; m < 4; ++m)                              \
        _Pragma("unroll") for (int n = 0; n < 2; ++n)                          \
        acc[m][n] = MFMA(af[m], bfr[n], acc[m][n]);                            \
  }

  if (!f32path) {
    stageA(0, 0);
    stageB(0, 0);
    stageA(32, 1);
    stageB(32, 1);
    for (int c = 0; c < 32; ++c) {
      const int buf = c % 3;
      if (c < 31) {
        asm volatile("s_waitcnt vmcnt(2)" ::: "memory");
      } else {
        asm volatile("s_waitcnt vmcnt(0)" ::: "memory");
      }
      __builtin_amdgcn_s_barrier();
      if (c < 30) {
        const int nb = (c + 2) % 3;
        stageA((c + 2) * 32, nb);
        stageB((c + 2) * 32, nb);
      }
      COMPUTE(buf)
    }
  } else {
    {
      const float4* p =
          reinterpret_cast<const float4*>(Av_f32 + (size_t)(bm + srow) * K + scol);
      STA8(0, cvt8(p[0], p[1]));
      stageB(0, 0);
    }
    __syncthreads();
    for (int c = 0; c < 32; ++c) {
      const int buf = c & 1;
      float4 fa[2];
      if (c < 31) {
        const int k1 = (c + 1) * 32;
        const float4* p = reinterpret_cast<const float4*>(
            Av_f32 + (size_t)(bm + srow) * K + k1 + scol);
        fa[0] = p[0];
        fa[1] = p[1];
        stageB(k1, buf ^ 1);
      }
      COMPUTE(buf)
      if (c < 31) {
        STA8(buf ^ 1, cvt8(fa[0], fa[1]));
      }
      __syncthreads();
    }
  }
#undef STA8
#undef RDOFF
#undef COMPUTE

#pragma unroll
  for (int m = 0; m < 4; ++m) {
    const int mr = bm + wr * 64 + m * 16 + lg * 4;
#pragma unroll
    for (int nt = 0; nt < 2; ++nt) {
      const int n = bn + wc * 32 + nt * 16 + lr;
      const float bb = bias[n];
      if (z == 0) {
#pragma unroll
        for (int r = 0; r < 4; ++r)
          Qb[(size_t)(mr + r) * N + n] = f2b((acc[m][nt][r] + bb) * qscale);
      } else if (z == 1) {
        // Kf: K[bh][s][d] -> bh*65536 + (d>>5)*32768 + (s>>4)*512
        //     + ((s&15)|(((d>>3)&3)<<4))*8 + (d&7)
        const int b2 = mr >> 10, s0 = mr & 1023, hh = n >> 6, dd = n & 63;
        const size_t base = (size_t)(b2 * 16 + hh) * 65536 + (size_t)(dd >> 5) * 32768 +
                            (size_t)(s0 >> 4) * 512 +
                            (size_t)((s0 & 15) | (((dd >> 3) & 3) << 4)) * 8 + (dd & 7);
#pragma unroll
        for (int r = 0; r < 4; ++r) Kf[base + r * 8] = f2b(acc[m][nt][r] + bb);
      } else {
        // Vf: V[bh][s][d] -> bh*65536 + (s>>5)*2048 + (d>>4)*512
        //     + ((d&15)|(((s>>3)&3)<<4))*8 + (s&7)
        const int b2 = mr >> 10, s0 = mr & 1023, hh = n >> 6, dd = n & 63;
        const size_t base = (size_t)(b2 * 16 + hh) * 65536 + (size_t)(s0 >> 5) * 2048 +
                            (size_t)(dd >> 4) * 512 +
                            (size_t)((dd & 15) | (((s0 >> 3) & 3) << 4)) * 8 + (s0 & 7);
        us4 pk;
#pragma unroll
        for (int r = 0; r < 4; ++r) pk[r] = f2b(acc[m][nt][r] + bb);
        *reinterpret_cast<us4*>(&Vf[base]) = pk;
      }
    }
  }
}

// Output projection v21 (unchanged): BM=128, BN=64, BK=64; 512 threads; A via
// glds, B staged directly from f32 wo (reg convert, T14 split).
__global__ __launch_bounds__(512, 4)
void gemm_out(const unsigned short* __restrict__ A, const float* __restrict__ Bwf,
              const float* __restrict__ bias, float* __restrict__ Out) {
  constexpr int K = 1024, N = 1024;
  __shared__ __align__(16) unsigned short As[2][128 * 64];
  __shared__ __align__(16) unsigned short Bs[2][64 * 64];
  const int lid = blockIdx.x + (blockIdx.y << 5);
  const int xcd = lid & 7, slot = lid >> 3;
  const int chunk = ((slot >> 5) << 3) + xcd;
  const int pos = slot & 31;
  const int bm = ((chunk << 1) + (pos >> 4)) * 128;
  const int bn = (pos & 15) * 64;
  const int t = threadIdx.x;
  const int w = t >> 6, lane = t & 63, lr = lane & 15, lg = lane >> 4;
  const int wr = w >> 1, wc = w & 1;
  const int swzc = (lr & 7) << 4;
  const int brow = t >> 3, bcol = (t & 7) * 8, bcb = (t & 7) * 16;

  f32x4 acc[2][2];
#pragma unroll
  for (int m = 0; m < 2; ++m)
#pragma unroll
    for (int n = 0; n < 2; ++n) acc[m][n] = f32x4{0.f, 0.f, 0.f, 0.f};

  auto stageA = [&](int k0, int buf) {
#pragma unroll
    for (int it = 0; it < 2; ++it) {
      const int s = it * 512 + t, row = s >> 3, cb = (s & 7) * 16;
      const char* g = (const char*)A + ((size_t)(bm + row) * 1024 + k0) * 2 +
                      (cb ^ ((row & 7) << 4));
      char* l = (char*)&As[buf][0] + (it * 512 + w * 64) * 16;
      glds16(g, l);
    }
  };
  float4 fb[2];
  auto loadB = [&](int k0) {
    const float4* p =
        reinterpret_cast<const float4*>(Bwf + (size_t)(bn + brow) * 1024 + k0 + bcol);
    fb[0] = p[0];
    fb[1] = p[1];
  };
  auto writeB = [&](int buf) {
    *reinterpret_cast<us8*>((char*)&Bs[buf][0] + brow * 128 +
                            (bcb ^ ((brow & 7) << 4))) = cvt8(fb[0], fb[1]);
  };

  stageA(0, 0);
  loadB(0);
  writeB(0);
  __syncthreads();

  for (int c = 0; c < 16; ++c) {
    const int buf = c & 1;
    if (c < 15) {
      const int k1 = (c + 1) * 64;
      stageA(k1, buf ^ 1);
      loadB(k1);
    }
#pragma unroll
    for (int h2 = 0; h2 < 2; ++h2) {
      bf16x8 af[2], bfr[2];
#pragma unroll
      for (int m = 0; m < 2; ++m) {
        const int row = wr * 32 + m * 16 + lr;
        af[m] = ldbf8((const unsigned short*)((char*)&As[buf][0] + row * 128 +
                                              ((h2 * 64 + lg * 16) ^ swzc)));
      }
#pragma unroll
      for (int n = 0; n < 2; ++n) {
        const int row = wc * 32 + n * 16 + lr;
        bfr[n] = ldbf8((const unsigned short*)((char*)&Bs[buf][0] + row * 128 +
                                               ((h2 * 64 + lg * 16) ^ swzc)));
      }
#pragma unroll
      for (int m = 0; m < 2; ++m)
#pragma unroll
        for (int n = 0; n < 2; ++n) acc[m][n] = MFMA(af[m], bfr[n], acc[m][n]);
    }
    if (c < 15) writeB(buf ^ 1);
    __syncthreads();
  }

#pragma unroll
  for (int m = 0; m < 2; ++m) {
    const int mr = bm + wr * 32 + m * 16 + lg * 4;
#pragma unroll
    for (int nt = 0; nt < 2; ++nt) {
      const int n = bn + wc * 32 + nt * 16 + lr;
      const float bb = bias[n];
#pragma unroll
      for (int r = 0; r < 4; ++r) Out[(size_t)(mr + r) * N + n] = acc[m][nt][r] + bb;
    }
  }
}

// Flash attention v14: 512-thread WG (8 waves = 8 q-tiles of one bh) sharing
// ONE K/V staging pass per chunk (2 glds/thread). Per-wave compute identical
// to v13: bit-mask C-init, fixed-offset softmax, cvt_pk, setprio, hoisted l.
// grid (64, 8) = 512 WGs -> 2 WG/CU x 8 waves = 16 waves/CU (unchanged).
__global__ __launch_bounds__(512, 4)
void attn_v14(const unsigned short* __restrict__ Qb,
              const unsigned short* __restrict__ Kf,
              const unsigned short* __restrict__ Vf,
              const unsigned short* __restrict__ Mfb,
              unsigned short* __restrict__ ctx) {
  // S[buf]: elems [0,2048) K half0, [2048,4096) K half1, [4096,8192) V. 16KB.
  __shared__ __align__(16) unsigned short S[2][8192];
  __shared__ __align__(16) unsigned short sP[8][1024];
  const int lid = blockIdx.x + (blockIdx.y << 6);   // [0,512)
  const int xcd = lid & 7, slot = lid >> 3;         // slot in [0,64)
  const int bh = ((slot >> 3) << 3) + xcd;          // [0,64)
  const int qp = slot & 7;                          // q-128-block [0,8)
  const int b = bh >> 4, h = bh & 15;
  const int t = threadIdx.x;                        // [0,512)
  const int w = t >> 6, wl = t & 63, lr = wl & 15, lg = wl >> 4;
  const int q0 = qp * 128 + w * 16;                 // wave's 16 q-rows
  const int swz = (lr & 7) << 4;

  const unsigned short* qp_ = Qb + (size_t)(b * 1024 + q0 + lr) * 1024 + h * 64 + lg * 8;
  const bf16x8 bq0 = ldbf8(qp_);
  const bf16x8 bq1 = ldbf8(qp_ + 32);

  const unsigned short* KfB = Kf + (size_t)bh * 65536;
  const unsigned short* VfB = Vf + (size_t)bh * 65536;
  // Mfb tile mt = (b*64 + qt)*16 + kc, qt = qp*8 + w; addr = mt*64 + wl.
  const unsigned short* mfp = Mfb + (size_t)((b * 64 + qp * 8 + w) * 16) * 64 + wl;

  f32x4 O[4];
  float l_ = 0.f;
#pragma unroll
  for (int dt = 0; dt < 4; ++dt) O[dt] = f32x4{0.f, 0.f, 0.f, 0.f};
  unsigned short* sp = &sP[w][0];

  // WG-cooperative staging: 2 glds/thread (K round + V round), linear dests.
  auto stage = [&](int kc, int buf) {
    // K round: waves 0-3 -> half0, waves 4-7 -> half1 (each 4KB)
    const unsigned short* gk = (w < 4)
        ? (KfB + kc * 2048 + (size_t)t * 8)
        : (KfB + 32768 + kc * 2048 + (size_t)(t - 256) * 8);
    glds16((const char*)gk, (char*)&S[buf][0] + w * 1024);
    // V round: 8KB linear
    glds16((const char*)(VfB + kc * 4096 + (size_t)t * 8),
           (char*)&S[buf][4096] + w * 1024);
  };

  stage(0, 0);
  __syncthreads();

  for (int kc = 0; kc < 16; ++kc) {
    const int buf = kc & 1;
    if (kc < 15) stage(kc + 1, buf ^ 1);

    const unsigned bits = mfp[kc * 64];

    bf16x8 ak[4][2];
#pragma unroll
    for (int t4 = 0; t4 < 4; ++t4) {
      ak[t4][0] = ldbf8(&S[buf][t4 * 512 + wl * 8]);
      ak[t4][1] = ldbf8(&S[buf][2048 + t4 * 512 + wl * 8]);
    }

    f32x4 sc[4];
    __builtin_amdgcn_s_setprio(1);
#pragma unroll
    for (int t4 = 0; t4 < 4; ++t4) {
      f32x4 a;
#pragma unroll
      for (int r = 0; r < 4; ++r)
        a[r] = (bits >> (t4 * 4 + r)) & 1u ? -1.4427e9f : -24.f;
      a = MFMA(ak[t4][0], bq0, a);
      a = MFMA(ak[t4][1], bq1, a);
      sc[t4] = a;
    }
    __builtin_amdgcn_s_setprio(0);

#pragma unroll
    for (int t4 = 0; t4 < 4; ++t4) {
      const float e0 = EXP2(sc[t4][0]), e1 = EXP2(sc[t4][1]);
      const float e2 = EXP2(sc[t4][2]), e3 = EXP2(sc[t4][3]);
      l_ += (e0 + e1) + (e2 + e3);
      uint2 pw;
      pw.x = cvtpk(e0, e1);
      pw.y = cvtpk(e2, e3);
      *reinterpret_cast<uint2*>((char*)sp + lr * 128 + ((t4 * 32 + lg * 8) ^ swz)) = pw;
    }

    __builtin_amdgcn_s_setprio(1);
#pragma unroll
    for (int ks = 0; ks < 2; ++ks) {
      bf16x8 ap =
          ldbf8((const unsigned short*)((char*)sp + lr * 128 + ((ks * 64 + lg * 16) ^ swz)));
#pragma unroll
      for (int dt = 0; dt < 4; ++dt) {
        bf16x8 bv = ldbf8(&S[buf][4096 + ks * 2048 + dt * 512 + wl * 8]);
        O[dt] = MFMA(ap, bv, O[dt]);
      }
    }
    __builtin_amdgcn_s_setprio(0);

    __syncthreads();
  }

  l_ += __shfl_xor(l_, 16);
  l_ += __shfl_xor(l_, 32);

  float linv[4];
#pragma unroll
  for (int r = 0; r < 4; ++r) linv[r] = 1.0f / __shfl(l_, lg * 4 + r);
#pragma unroll
  for (int dt = 0; dt < 4; ++dt)
#pragma unroll
    for (int r = 0; r < 4; ++r)
      ctx[(size_t)(b * 1024 + q0 + lg * 4 + r) * 1024 + h * 64 + dt * 16 + lr] =
          f2b(O[dt][r] * linv[r]);
}

extern "C" void kernel_launch(void* const* d_in, const int* in_sizes, int n_in,
                              void* d_out, int out_size, void* d_ws, size_t ws_size,
                              hipStream_t stream) {
  const float* query = (const float*)d_in[0];
  const float* key   = (const float*)d_in[1];
  const float* value = (const float*)d_in[2];
  const int*   mask  = (const int*)d_in[3];
  const float* wq = (const float*)d_in[4];
  const float* bq = (const float*)d_in[5];
  const float* wk = (const float*)d_in[6];
  const float* bk = (const float*)d_in[7];
  const float* wv = (const float*)d_in[8];
  const float* bv = (const float*)d_in[9];
  const float* wo = (const float*)d_in[10];
  const float* bo = (const float*)d_in[11];
  float* out = (float*)d_out;

  // ws [0..32MB): Qb, Kf, Vf, ctx (bf16, 8MB each). ctx slot doubles as Abfk
  // during the projection. d_out: Abfq [0,8MB) + Wb [8,14MB) + Mfb [14,14.5MB).
  // Abfv at ws+32MB only if ws_size >= 40MB. gemm_out reads wo (f32) directly.
  const size_t SZ = (size_t)4096 * 1024;
  unsigned short* Qb   = (unsigned short*)d_ws;
  unsigned short* Kf   = Qb + SZ;
  unsigned short* Vf   = Kf + SZ;
  unsigned short* ctx  = Vf + SZ;
  unsigned short* Abfq = (unsigned short*)d_out;
  unsigned short* Wb   = Abfq + SZ;
  unsigned short* Mfb  = (unsigned short*)((char*)d_out + (size_t)14 * 1024 * 1024);
  unsigned short* Abfk = ctx;                     // before attn
  const bool big = ws_size >= (size_t)40 * 1024 * 1024;
  unsigned short* Abfv = big ? (ctx + SZ) : nullptr;  // ws+32MB
  const int nconv = big ? 7680 : 5632;

  const float qscale = 0.125f * 1.4426950408889634f;  // 1/sqrt(64) * log2(e)
  dim3 blk(256);
  prep<<<nconv + 1024, blk, 0, stream>>>(query, key, value, wq, wk, wv, mask,
                                         Abfq, Abfk, Abfv, Wb, Mfb, nconv);
  gemm_proj<<<dim3(32, 8, 3), dim3(512), 0, stream>>>(Abfq, Abfk, Abfv, value, Wb,
                                                      bq, bk, bv, Qb, Kf, Vf, qscale);
  attn_v14<<<dim3(64, 8), dim3(512), 0, stream>>>(Qb, Kf, Vf, Mfb, ctx);
  gemm_out<<<dim3(32, 16), dim3(512), 0, stream>>>(ctx, wo, bo, out);
}

// Round 26
// 104.161 us; speedup vs baseline: 1.1128x; 1.0091x over previous
//
#include <hip/hip_runtime.h>
#include <hip/hip_bf16.h>

// MHA forward: B=4, S=1024, D=1024, H=16, DK=64.
// v26: R25 base (105.1us) + attn_v15: counted-vmcnt 3-buffer K/V staging
// (vmcnt(2)+s_barrier, no full drain — sP is wave-private so the barrier only
// orders S reuse). gemm_proj/gemm_out/prep unchanged.

typedef __bf16 bf16x8 __attribute__((ext_vector_type(8)));
typedef float f32x4 __attribute__((ext_vector_type(4)));
typedef unsigned short us8 __attribute__((ext_vector_type(8)));
typedef unsigned short us4 __attribute__((ext_vector_type(4)));

#define MFMA(a, b, c) __builtin_amdgcn_mfma_f32_16x16x32_bf16(a, b, c, 0, 0, 0)
#define EXP2(x) __builtin_amdgcn_exp2f(x)

__device__ __forceinline__ unsigned short f2b(float f) {
  return __builtin_bit_cast(unsigned short, __float2bfloat16(f));
}
__device__ __forceinline__ unsigned cvtpk(float lo, float hi) {
  unsigned r;
  asm("v_cvt_pk_bf16_f32 %0, %1, %2" : "=v"(r) : "v"(lo), "v"(hi));
  return r;
}
__device__ __forceinline__ bf16x8 ldbf8(const unsigned short* p) {
  return __builtin_bit_cast(bf16x8, *reinterpret_cast<const us8*>(p));
}
__device__ __forceinline__ us8 cvt8(float4 a, float4 b) {
  us8 o;
  o[0] = f2b(a.x); o[1] = f2b(a.y); o[2] = f2b(a.z); o[3] = f2b(a.w);
  o[4] = f2b(b.x); o[5] = f2b(b.y); o[6] = f2b(b.z); o[7] = f2b(b.w);
  return o;
}
__device__ __forceinline__ void glds16(const void* g, void* l) {
  __builtin_amdgcn_global_load_lds(
      (const __attribute__((address_space(1))) unsigned int*)g,
      (__attribute__((address_space(3))) unsigned int*)l, 16, 0, 0);
}

// prep (fused): bid [0,1536): wq/wk/wv f32->bf16 -> Wb.
//   [1536,3584): query -> Abfq; [3584,5632): key -> Abfk;
//   [5632,nconv): value -> Abfv (only when ws big).
//   [nconv, nconv+1024): mask bit-pack -> Mfb.
__global__ __launch_bounds__(256)
void prep(const float* __restrict__ query, const float* __restrict__ key,
          const float* __restrict__ value, const float* __restrict__ wq,
          const float* __restrict__ wk, const float* __restrict__ wv,
          const int* __restrict__ mask,
          unsigned short* __restrict__ Abfq, unsigned short* __restrict__ Abfk,
          unsigned short* __restrict__ Abfv, unsigned short* __restrict__ Wb,
          unsigned short* __restrict__ Mfb, int nconv) {
  const int bid = blockIdx.x, tid = threadIdx.x;
  if (bid >= nconv) {
    const int mt = (bid - nconv) * 4 + (tid >> 6);
    const int wl = tid & 63, lr = wl & 15, lg = wl >> 4;
    const int kc = mt & 15, qt = (mt >> 4) & 63, b = mt >> 10;
    const int* mrow = mask + (size_t)(b * 1024 + qt * 16 + lr) * 1024 + kc * 64 + lg * 4;
    unsigned bits = 0;
#pragma unroll
    for (int t4 = 0; t4 < 4; ++t4) {
      const int4 mv = *reinterpret_cast<const int4*>(mrow + t4 * 16);
      bits |= (mv.x != 0 ? 1u : 0u) << (t4 * 4 + 0);
      bits |= (mv.y != 0 ? 1u : 0u) << (t4 * 4 + 1);
      bits |= (mv.z != 0 ? 1u : 0u) << (t4 * 4 + 2);
      bits |= (mv.w != 0 ? 1u : 0u) << (t4 * 4 + 3);
    }
    Mfb[(size_t)mt * 64 + wl] = (unsigned short)bits;
    return;
  }
  const float* src;
  unsigned short* dst;
  size_t off;
  if (bid < 1536) {
    const int widx = bid >> 9;
    src = (widx == 0) ? wq : (widx == 1) ? wk : wv;
    dst = Wb + (size_t)widx * 1048576;
    off = (size_t)(bid & 511) * 2048 + tid * 8;
  } else if (bid < 3584) {
    src = query; dst = Abfq; off = (size_t)(bid - 1536) * 2048 + tid * 8;
  } else if (bid < 5632) {
    src = key; dst = Abfk; off = (size_t)(bid - 3584) * 2048 + tid * 8;
  } else {
    src = value; dst = Abfv; off = (size_t)(bid - 5632) * 2048 + tid * 8;
  }
  const float4* p = reinterpret_cast<const float4*>(src + off);
  *reinterpret_cast<us8*>(dst + off) = cvt8(p[0], p[1]);
}

// Projection GEMM v22 (unchanged): BM=128, BN=128, BK=32; 512 threads; 3-buf
// counted-vmcnt pipeline; conflict-free row-pair-interleaved LDS layout.
__global__ __launch_bounds__(512, 6)
void gemm_proj(const unsigned short* __restrict__ Aq,
               const unsigned short* __restrict__ Ak,
               const unsigned short* __restrict__ Av_bf,
               const float* __restrict__ Av_f32,
               const unsigned short* __restrict__ Wb,
               const float* __restrict__ bq, const float* __restrict__ bk,
               const float* __restrict__ bv, unsigned short* __restrict__ Qb,
               unsigned short* __restrict__ Kf, unsigned short* __restrict__ Vf,
               float qscale) {
  constexpr int K = 1024, N = 1024;
  __shared__ __align__(16) unsigned short As[3][128 * 32];
  __shared__ __align__(16) unsigned short Bs[3][128 * 32];
  const int lid = blockIdx.x + (blockIdx.y << 5) + (blockIdx.z << 8);
  const int xcd = lid & 7, slot = lid >> 3;
  const int chunk = ((slot >> 3) << 3) + xcd;
  const int z = chunk >> 5;
  const int bm = (chunk & 31) * 128;
  const int bn = (slot & 7) * 128;

  const unsigned short* Abf = (z == 0) ? Aq : (z == 1) ? Ak : Av_bf;
  const bool f32path = (z == 2) && (Av_bf == nullptr);
  const unsigned short* Bw = Wb + (size_t)z * 1048576;
  const float* bias = (z == 0) ? bq : (z == 1) ? bk : bv;
  const int t = threadIdx.x;
  const int w = t >> 6, lane = t & 63, lr = lane & 15, lg = lane >> 4;
  const int wr = w >> 2, wc = w & 3;

  const int sline = t >> 3;
  const int su = (t & 7) ^ (sline & 7);
  const int srow = sline * 2 + (su >> 2);
  const int scol = (su & 3) * 8;

  f32x4 acc[4][2];
#pragma unroll
  for (int m = 0; m < 4; ++m)
#pragma unroll
    for (int n = 0; n < 2; ++n) acc[m][n] = f32x4{0.f, 0.f, 0.f, 0.f};

  auto stageA = [&](int k0, int buf) {
    const char* g = (const char*)(Abf + (size_t)(bm + srow) * 1024 + k0 + scol);
    char* l = (char*)&As[buf][0] + (w * 64) * 16;
    glds16(g, l);
  };
  auto stageB = [&](int k0, int buf) {
    const char* g = (const char*)(Bw + (size_t)(bn + srow) * 1024 + k0 + scol);
    char* l = (char*)&Bs[buf][0] + (w * 64) * 16;
    glds16(g, l);
  };
#define STA8(buf, v)                                                           \
  { *reinterpret_cast<us8*>((char*)&As[buf][0] + t * 16) = (v); }
#define RDOFF(row) (((row) >> 1) * 128 +                                       \
                    (((lg | (((row) & 1) << 2)) ^ (((row) >> 1) & 7)) * 16))
#define COMPUTE(buf)                                                           \
  {                                                                            \
    bf16x8 af[4], bfr[2];                                                      \
    _Pragma("unroll") for (int m = 0; m < 4; ++m) {                            \
      const int row = wr * 64 + m * 16 + lr;                                   \
      af[m] = ldbf8((const unsigned short*)((char*)&As[buf][0] + RDOFF(row))); \
    }                                                                          \
    _Pragma("unroll") for (int n = 0; n < 2; ++n) {                            \
      const int row = wc * 32 + n * 16 + lr;                                   \
      bfr[n] = ldbf8((const unsigned short*)((char*)&Bs[buf][0] + RDOFF(row)));\
    }                                                                          \
    _Pragma("unroll") for (int m = 0; m < 4; ++m)                              \
        _Pragma("unroll") for (int n = 0; n < 2; ++n)                          \
        acc[m][n] = MFMA(af[m], bfr[n], acc[m][n]);                            \
  }

  if (!f32path) {
    stageA(0, 0);
    stageB(0, 0);
    stageA(32, 1);
    stageB(32, 1);
    for (int c = 0; c < 32; ++c) {
      const int buf = c % 3;
      if (c < 31) {
        asm volatile("s_waitcnt vmcnt(2)" ::: "memory");
      } else {
        asm volatile("s_waitcnt vmcnt(0)" ::: "memory");
      }
      __builtin_amdgcn_s_barrier();
      if (c < 30) {
        const int nb = (c + 2) % 3;
        stageA((c + 2) * 32, nb);
        stageB((c + 2) * 32, nb);
      }
      COMPUTE(buf)
    }
  } else {
    {
      const float4* p =
          reinterpret_cast<const float4*>(Av_f32 + (size_t)(bm + srow) * K + scol);
      STA8(0, cvt8(p[0], p[1]));
      stageB(0, 0);
    }
    __syncthreads();
    for (int c = 0; c < 32; ++c) {
      const int buf = c & 1;
      float4 fa[2];
      if (c < 31) {
        const int k1 = (c + 1) * 32;
        const float4* p = reinterpret_cast<const float4*>(
            Av_f32 + (size_t)(bm + srow) * K + k1 + scol);
        fa[0] = p[0];
        fa[1] = p[1];
        stageB(k1, buf ^ 1);
      }
      COMPUTE(buf)
      if (c < 31) {
        STA8(buf ^ 1, cvt8(fa[0], fa[1]));
      }
      __syncthreads();
    }
  }
#undef STA8
#undef RDOFF
#undef COMPUTE

#pragma unroll
  for (int m = 0; m < 4; ++m) {
    const int mr = bm + wr * 64 + m * 16 + lg * 4;
#pragma unroll
    for (int nt = 0; nt < 2; ++nt) {
      const int n = bn + wc * 32 + nt * 16 + lr;
      const float bb = bias[n];
      if (z == 0) {
#pragma unroll
        for (int r = 0; r < 4; ++r)
          Qb[(size_t)(mr + r) * N + n] = f2b((acc[m][nt][r] + bb) * qscale);
      } else if (z == 1) {
        // Kf: K[bh][s][d] -> bh*65536 + (d>>5)*32768 + (s>>4)*512
        //     + ((s&15)|(((d>>3)&3)<<4))*8 + (d&7)
        const int b2 = mr >> 10, s0 = mr & 1023, hh = n >> 6, dd = n & 63;
        const size_t base = (size_t)(b2 * 16 + hh) * 65536 + (size_t)(dd >> 5) * 32768 +
                            (size_t)(s0 >> 4) * 512 +
                            (size_t)((s0 & 15) | (((dd >> 3) & 3) << 4)) * 8 + (dd & 7);
#pragma unroll
        for (int r = 0; r < 4; ++r) Kf[base + r * 8] = f2b(acc[m][nt][r] + bb);
      } else {
        // Vf: V[bh][s][d] -> bh*65536 + (s>>5)*2048 + (d>>4)*512
        //     + ((d&15)|(((s>>3)&3)<<4))*8 + (s&7)
        const int b2 = mr >> 10, s0 = mr & 1023, hh = n >> 6, dd = n & 63;
        const size_t base = (size_t)(b2 * 16 + hh) * 65536 + (size_t)(s0 >> 5) * 2048 +
                            (size_t)(dd >> 4) * 512 +
                            (size_t)((dd & 15) | (((s0 >> 3) & 3) << 4)) * 8 + (s0 & 7);
        us4 pk;
#pragma unroll
        for (int r = 0; r < 4; ++r) pk[r] = f2b(acc[m][nt][r] + bb);
        *reinterpret_cast<us4*>(&Vf[base]) = pk;
      }
    }
  }
}

// Output projection v21 (unchanged): BM=128, BN=64, BK=64; 512 threads; A via
// glds, B staged directly from f32 wo (reg convert, T14 split).
__global__ __launch_bounds__(512, 4)
void gemm_out(const unsigned short* __restrict__ A, const float* __restrict__ Bwf,
              const float* __restrict__ bias, float* __restrict__ Out) {
  constexpr int K = 1024, N = 1024;
  __shared__ __align__(16) unsigned short As[2][128 * 64];
  __shared__ __align__(16) unsigned short Bs[2][64 * 64];
  const int lid = blockIdx.x + (blockIdx.y << 5);
  const int xcd = lid & 7, slot = lid >> 3;
  const int chunk = ((slot >> 5) << 3) + xcd;
  const int pos = slot & 31;
  const int bm = ((chunk << 1) + (pos >> 4)) * 128;
  const int bn = (pos & 15) * 64;
  const int t = threadIdx.x;
  const int w = t >> 6, lane = t & 63, lr = lane & 15, lg = lane >> 4;
  const int wr = w >> 1, wc = w & 1;
  const int swzc = (lr & 7) << 4;
  const int brow = t >> 3, bcol = (t & 7) * 8, bcb = (t & 7) * 16;

  f32x4 acc[2][2];
#pragma unroll
  for (int m = 0; m < 2; ++m)
#pragma unroll
    for (int n = 0; n < 2; ++n) acc[m][n] = f32x4{0.f, 0.f, 0.f, 0.f};

  auto stageA = [&](int k0, int buf) {
#pragma unroll
    for (int it = 0; it < 2; ++it) {
      const int s = it * 512 + t, row = s >> 3, cb = (s & 7) * 16;
      const char* g = (const char*)A + ((size_t)(bm + row) * 1024 + k0) * 2 +
                      (cb ^ ((row & 7) << 4));
      char* l = (char*)&As[buf][0] + (it * 512 + w * 64) * 16;
      glds16(g, l);
    }
  };
  float4 fb[2];
  auto loadB = [&](int k0) {
    const float4* p =
        reinterpret_cast<const float4*>(Bwf + (size_t)(bn + brow) * 1024 + k0 + bcol);
    fb[0] = p[0];
    fb[1] = p[1];
  };
  auto writeB = [&](int buf) {
    *reinterpret_cast<us8*>((char*)&Bs[buf][0] + brow * 128 +
                            (bcb ^ ((brow & 7) << 4))) = cvt8(fb[0], fb[1]);
  };

  stageA(0, 0);
  loadB(0);
  writeB(0);
  __syncthreads();

  for (int c = 0; c < 16; ++c) {
    const int buf = c & 1;
    if (c < 15) {
      const int k1 = (c + 1) * 64;
      stageA(k1, buf ^ 1);
      loadB(k1);
    }
#pragma unroll
    for (int h2 = 0; h2 < 2; ++h2) {
      bf16x8 af[2], bfr[2];
#pragma unroll
      for (int m = 0; m < 2; ++m) {
        const int row = wr * 32 + m * 16 + lr;
        af[m] = ldbf8((const unsigned short*)((char*)&As[buf][0] + row * 128 +
                                              ((h2 * 64 + lg * 16) ^ swzc)));
      }
#pragma unroll
      for (int n = 0; n < 2; ++n) {
        const int row = wc * 32 + n * 16 + lr;
        bfr[n] = ldbf8((const unsigned short*)((char*)&Bs[buf][0] + row * 128 +
                                               ((h2 * 64 + lg * 16) ^ swzc)));
      }
#pragma unroll
      for (int m = 0; m < 2; ++m)
#pragma unroll
        for (int n = 0; n < 2; ++n) acc[m][n] = MFMA(af[m], bfr[n], acc[m][n]);
    }
    if (c < 15) writeB(buf ^ 1);
    __syncthreads();
  }

#pragma unroll
  for (int m = 0; m < 2; ++m) {
    const int mr = bm + wr * 32 + m * 16 + lg * 4;
#pragma unroll
    for (int nt = 0; nt < 2; ++nt) {
      const int n = bn + wc * 32 + nt * 16 + lr;
      const float bb = bias[n];
#pragma unroll
      for (int r = 0; r < 4; ++r) Out[(size_t)(mr + r) * N + n] = acc[m][nt][r] + bb;
    }
  }
}

// Flash attention v15: v14 (512-thread shared staging) with counted-vmcnt
// 3-buffer pipeline — vmcnt(2) + s_barrier per chunk, prefetch 2 ahead,
// no full glds drain. sP is wave-private (no cross-wave hazard).
__global__ __launch_bounds__(512, 2)
void attn_v15(const unsigned short* __restrict__ Qb,
              const unsigned short* __restrict__ Kf,
              const unsigned short* __restrict__ Vf,
              const unsigned short* __restrict__ Mfb,
              unsigned short* __restrict__ ctx) {
  // S[buf]: elems [0,2048) K half0, [2048,4096) K half1, [4096,8192) V. 16KB.
  __shared__ __align__(16) unsigned short S[3][8192];   // 48KB
  __shared__ __align__(16) unsigned short sP[8][1024];  // 16KB
  const int lid = blockIdx.x + (blockIdx.y << 6);
  const int xcd = lid & 7, slot = lid >> 3;
  const int bh = ((slot >> 3) << 3) + xcd;
  const int qp = slot & 7;
  const int b = bh >> 4, h = bh & 15;
  const int t = threadIdx.x;
  const int w = t >> 6, wl = t & 63, lr = wl & 15, lg = wl >> 4;
  const int q0 = qp * 128 + w * 16;
  const int swz = (lr & 7) << 4;

  const unsigned short* qp_ = Qb + (size_t)(b * 1024 + q0 + lr) * 1024 + h * 64 + lg * 8;
  const bf16x8 bq0 = ldbf8(qp_);
  const bf16x8 bq1 = ldbf8(qp_ + 32);

  const unsigned short* KfB = Kf + (size_t)bh * 65536;
  const unsigned short* VfB = Vf + (size_t)bh * 65536;
  const unsigned short* mfp = Mfb + (size_t)((b * 64 + qp * 8 + w) * 16) * 64 + wl;

  f32x4 O[4];
  float l_ = 0.f;
#pragma unroll
  for (int dt = 0; dt < 4; ++dt) O[dt] = f32x4{0.f, 0.f, 0.f, 0.f};
  unsigned short* sp = &sP[w][0];

  // WG-cooperative staging: 2 glds/thread (K round + V round), linear dests.
  auto stage = [&](int kc, int buf) {
    const unsigned short* gk = (w < 4)
        ? (KfB + kc * 2048 + (size_t)t * 8)
        : (KfB + 32768 + kc * 2048 + (size_t)(t - 256) * 8);
    glds16((const char*)gk, (char*)&S[buf][0] + w * 1024);
    glds16((const char*)(VfB + kc * 4096 + (size_t)t * 8),
           (char*)&S[buf][4096] + w * 1024);
  };

  stage(0, 0);
  stage(1, 1);

  for (int kc = 0; kc < 16; ++kc) {
    const int buf = kc % 3;
    if (kc < 15) {
      asm volatile("s_waitcnt vmcnt(2)" ::: "memory");  // chunk kc landed
    } else {
      asm volatile("s_waitcnt vmcnt(0)" ::: "memory");
    }
    __builtin_amdgcn_s_barrier();  // all waves: kc landed; kc-1 reads done
    if (kc < 14) stage(kc + 2, (kc + 2) % 3);

    const unsigned bits = mfp[kc * 64];

    bf16x8 ak[4][2];
#pragma unroll
    for (int t4 = 0; t4 < 4; ++t4) {
      ak[t4][0] = ldbf8(&S[buf][t4 * 512 + wl * 8]);
      ak[t4][1] = ldbf8(&S[buf][2048 + t4 * 512 + wl * 8]);
    }

    f32x4 sc[4];
    __builtin_amdgcn_s_setprio(1);
#pragma unroll
    for (int t4 = 0; t4 < 4; ++t4) {
      f32x4 a;
#pragma unroll
      for (int r = 0; r < 4; ++r)
        a[r] = (bits >> (t4 * 4 + r)) & 1u ? -1.4427e9f : -24.f;
      a = MFMA(ak[t4][0], bq0, a);
      a = MFMA(ak[t4][1], bq1, a);
      sc[t4] = a;
    }
    __builtin_amdgcn_s_setprio(0);

#pragma unroll
    for (int t4 = 0; t4 < 4; ++t4) {
      const float e0 = EXP2(sc[t4][0]), e1 = EXP2(sc[t4][1]);
      const float e2 = EXP2(sc[t4][2]), e3 = EXP2(sc[t4][3]);
      l_ += (e0 + e1) + (e2 + e3);
      uint2 pw;
      pw.x = cvtpk(e0, e1);
      pw.y = cvtpk(e2, e3);
      *reinterpret_cast<uint2*>((char*)sp + lr * 128 + ((t4 * 32 + lg * 8) ^ swz)) = pw;
    }

    __builtin_amdgcn_s_setprio(1);
#pragma unroll
    for (int ks = 0; ks < 2; ++ks) {
      bf16x8 ap =
          ldbf8((const unsigned short*)((char*)sp + lr * 128 + ((ks * 64 + lg * 16) ^ swz)));
#pragma unroll
      for (int dt = 0; dt < 4; ++dt) {
        bf16x8 bv = ldbf8(&S[buf][4096 + ks * 2048 + dt * 512 + wl * 8]);
        O[dt] = MFMA(ap, bv, O[dt]);
      }
    }
    __builtin_amdgcn_s_setprio(0);
  }

  l_ += __shfl_xor(l_, 16);
  l_ += __shfl_xor(l_, 32);

  float linv[4];
#pragma unroll
  for (int r = 0; r < 4; ++r) linv[r] = 1.0f / __shfl(l_, lg * 4 + r);
#pragma unroll
  for (int dt = 0; dt < 4; ++dt)
#pragma unroll
    for (int r = 0; r < 4; ++r)
      ctx[(size_t)(b * 1024 + q0 + lg * 4 + r) * 1024 + h * 64 + dt * 16 + lr] =
          f2b(O[dt][r] * linv[r]);
}

extern "C" void kernel_launch(void* const* d_in, const int* in_sizes, int n_in,
                              void* d_out, int out_size, void* d_ws, size_t ws_size,
                              hipStream_t stream) {
  const float* query = (const float*)d_in[0];
  const float* key   = (const float*)d_in[1];
  const float* value = (const float*)d_in[2];
  const int*   mask  = (const int*)d_in[3];
  const float* wq = (const float*)d_in[4];
  const float* bq = (const float*)d_in[5];
  const float* wk = (const float*)d_in[6];
  const float* bk = (const float*)d_in[7];
  const float* wv = (const float*)d_in[8];
  const float* bv = (const float*)d_in[9];
  const float* wo = (const float*)d_in[10];
  const float* bo = (const float*)d_in[11];
  float* out = (float*)d_out;

  // ws [0..32MB): Qb, Kf, Vf, ctx (bf16, 8MB each). ctx slot doubles as Abfk
  // during the projection. d_out: Abfq [0,8MB) + Wb [8,14MB) + Mfb [14,14.5MB).
  // Abfv at ws+32MB only if ws_size >= 40MB. gemm_out reads wo (f32) directly.
  const size_t SZ = (size_t)4096 * 1024;
  unsigned short* Qb   = (unsigned short*)d_ws;
  unsigned short* Kf   = Qb + SZ;
  unsigned short* Vf   = Kf + SZ;
  unsigned short* ctx  = Vf + SZ;
  unsigned short* Abfq = (unsigned short*)d_out;
  unsigned short* Wb   = Abfq + SZ;
  unsigned short* Mfb  = (unsigned short*)((char*)d_out + (size_t)14 * 1024 * 1024);
  unsigned short* Abfk = ctx;                     // before attn
  const bool big = ws_size >= (size_t)40 * 1024 * 1024;
  unsigned short* Abfv = big ? (ctx + SZ) : nullptr;  // ws+32MB
  const int nconv = big ? 7680 : 5632;

  const float qscale = 0.125f * 1.4426950408889634f;  // 1/sqrt(64) * log2(e)
  dim3 blk(256);
  prep<<<nconv + 1024, blk, 0, stream>>>(query, key, value, wq, wk, wv, mask,
                                         Abfq, Abfk, Abfv, Wb, Mfb, nconv);
  gemm_proj<<<dim3(32, 8, 3), dim3(512), 0, stream>>>(Abfq, Abfk, Abfv, value, Wb,
                                                      bq, bk, bv, Qb, Kf, Vf, qscale);
  attn_v15<<<dim3(64, 8), dim3(512), 0, stream>>>(Qb, Kf, Vf, Mfb, ctx);
  gemm_out<<<dim3(32, 16), dim3(512), 0, stream>>>(ctx, wo, bo, out);
}